// Round 6
// baseline (7933.515 us; speedup 1.0000x reference)
//
#include <hip/hip_runtime.h>
#include <hip/hip_bf16.h>

typedef _Float16 f16x2 __attribute__((ext_vector_type(2)));

#define HID 300
#define NSEQ 64
#define NROWS 4096   // B*N = 64*64

union U { uint4 u; f16x2 h[4]; };

__device__ __forceinline__ float sigm(float x){ return 1.f/(1.f+__expf(-x)); }

__device__ __forceinline__ float fdot2a(f16x2 a, f16x2 b, float c){
#if __has_builtin(__builtin_amdgcn_fdot2)
  return __builtin_amdgcn_fdot2(a, b, c, false);
#else
  return c + (float)a.x*(float)b.x + (float)a.y*(float)b.y;
#endif
}

// Relaxed agent-scope ops: LLC-coherent, NO cache maintenance (no L2 flush).
__device__ __forceinline__ void xstore(float* p, float v){
  __hip_atomic_store(p, v, __ATOMIC_RELAXED, __HIP_MEMORY_SCOPE_AGENT);
}
__device__ __forceinline__ float xload(const float* p){
  return __hip_atomic_load(p, __ATOMIC_RELAXED, __HIP_MEMORY_SCOPE_AGENT);
}
__device__ __forceinline__ int xloadi(const int* p){
  return __hip_atomic_load(p, __ATOMIC_RELAXED, __HIP_MEMORY_SCOPE_AGENT);
}

// sync area layout (ints):
//   [0, 1536)            : cross-layer step counters (3 layers x 32 pairs x 16)
//   [1536, 1536+4096)    : fE flags (h-exchange, 128 pairs x 2 halves x 16)
//   [13824, 13824+64)    : claim pools (4 layers x 16)   (gap kept zeroed)
#define NSYNC (3*32*16 + 3*128*2*16 + 64)

// P-chunk: rows opmP1/opmP2 of Wp against xh[np], accumulating in 16 scalars.
#define PCH(K0,K1) \
  for (int kg=(K0); kg<(K1); ++kg){ \
    U v1; v1.u = Wp4[(size_t)kg*1800 + opmP1]; \
    U v2; if (hasP2) v2.u = Wp4[(size_t)kg*1800 + opmP2]; \
    f16x2 xA0=xh[np][0][kg*4+0],xA1=xh[np][0][kg*4+1],xA2=xh[np][0][kg*4+2],xA3=xh[np][0][kg*4+3]; \
    f16x2 xB0=xh[np][1][kg*4+0],xB1=xh[np][1][kg*4+1],xB2=xh[np][1][kg*4+2],xB3=xh[np][1][kg*4+3]; \
    p1a0=fdot2a(v1.h[0],xA0,p1a0); p1a1=fdot2a(v1.h[1],xA1,p1a1); \
    p1a2=fdot2a(v1.h[2],xA2,p1a2); p1a3=fdot2a(v1.h[3],xA3,p1a3); \
    p1b0=fdot2a(v1.h[0],xB0,p1b0); p1b1=fdot2a(v1.h[1],xB1,p1b1); \
    p1b2=fdot2a(v1.h[2],xB2,p1b2); p1b3=fdot2a(v1.h[3],xB3,p1b3); \
    if (hasP2){ \
      p2a0=fdot2a(v2.h[0],xA0,p2a0); p2a1=fdot2a(v2.h[1],xA1,p2a1); \
      p2a2=fdot2a(v2.h[2],xA2,p2a2); p2a3=fdot2a(v2.h[3],xA3,p2a3); \
      p2b0=fdot2a(v2.h[0],xB0,p2b0); p2b1=fdot2a(v2.h[1],xB1,p2b1); \
      p2b2=fdot2a(v2.h[2],xB2,p2b2); p2b3=fdot2a(v2.h[3],xB3,p2b3); \
    } \
  }

// ---------------------------------------------------------------------------
// Merged repack: f32 -> fp16 pairs, [kg][outs][4 pairs] coalesced; also zeroes
// the pipeline sync counters + claim pools every launch.
// ---------------------------------------------------------------------------
__global__ void convert_all_kernel(
    const float* __restrict__ whh_c, const float* __restrict__ wih_p,
    const float* __restrict__ wih_c, const float* __restrict__ whh_p,
    const float* __restrict__ wr0,   const float* __restrict__ wr1,
    const float* __restrict__ w_in,  const float* __restrict__ w1,
    const float* __restrict__ w2,
    f16x2* __restrict__ W_M4, f16x2* __restrict__ WrT4, f16x2* __restrict__ W_P4,
    f16x2* __restrict__ W_H4, f16x2* __restrict__ W_14, f16x2* __restrict__ W_24,
    int* __restrict__ syncc)
{
  const int NA = 4*38*1800*4;
  const int NB = 4*38*600*4;
  const int NP = 4*38*1800*4;
  const int NH = 128*300*4;
  const int N1 = 318*304*4;
  const int N2 = 38*304*4;
  const int NS = NSYNC;
  const int TOT = NA+NB+NP+NH+N1+N2+NS;
  for (int idx0 = blockIdx.x*blockDim.x + threadIdx.x; idx0 < TOT; idx0 += gridDim.x*blockDim.x){
    int idx = idx0;
    if (idx < NA){
      int l    = idx/(38*1800*4);
      int rem  = idx - l*(38*1800*4);
      int kg   = rem/(1800*4);
      int rem2 = rem - kg*(1800*4);
      int o = rem2>>2, s = rem2&3;
      int c = (kg*4+s)*2;
      float v0=0.f, v1=0.f;
      if (c < 300){
        const float* src = (o<900) ? (whh_c + ((size_t)l*900+o)*300)
                                   : (wih_p + ((size_t)l*900+(o-900))*300);
        v0 = src[c]; v1 = src[c+1];
      }
      f16x2 t; t.x=(_Float16)v0; t.y=(_Float16)v1;
      W_M4[idx] = t; continue;
    }
    idx -= NA;
    if (idx < NB){
      int l    = idx/(38*600*4);
      int rem  = idx - l*(38*600*4);
      int kg   = rem/(600*4);
      int rem2 = rem - kg*(600*4);
      int t6 = rem2>>2, s = rem2&3;
      int d = t6>>1, hh = t6&1;
      int c = (kg*4+s)*2;
      float v0=0.f, v1=0.f;
      if (c < 300){
        const float* src = hh ? (wr1 + ((size_t)l*300+d)*300)
                              : (wr0 + ((size_t)l*300+d)*300);
        v0 = src[c]; v1 = src[c+1];
      }
      f16x2 t; t.x=(_Float16)v0; t.y=(_Float16)v1;
      WrT4[idx] = t; continue;
    }
    idx -= NB;
    if (idx < NP){
      int l    = idx/(38*1800*4);
      int rem  = idx - l*(38*1800*4);
      int kg   = rem/(1800*4);
      int rem2 = rem - kg*(1800*4);
      int o = rem2>>2, s = rem2&3;
      int c = (kg*4+s)*2;
      float v0=0.f, v1=0.f;
      if (c < 300){
        const float* src = (o<900) ? (wih_c + ((size_t)l*900+o)*300)
                                   : (whh_p + ((size_t)l*900+(o-900))*300);
        v0 = src[c]; v1 = src[c+1];
      }
      f16x2 t; t.x=(_Float16)v0; t.y=(_Float16)v1;
      W_P4[idx] = t; continue;
    }
    idx -= NP;
    if (idx < NH){
      int kg  = idx/(300*4);
      int rem = idx - kg*(300*4);
      int o = rem>>2, s = rem&3;
      int c = (kg*4+s)*2;
      f16x2 t; t.x=(_Float16)w_in[(size_t)o*1024+c]; t.y=(_Float16)w_in[(size_t)o*1024+c+1];
      W_H4[idx] = t; continue;
    }
    idx -= NH;
    if (idx < N1){
      int kgg = idx/(304*4);
      int rem = idx - kgg*(304*4);
      int o = rem>>2, s = rem&3;
      int segbase, seglen, kgl;
      if (kgg < 190){ int seg = kgg/38; kgl = kgg - seg*38; segbase = seg*300; seglen = 300; }
      else { int kk = kgg-190; int sf = kk>>6; kgl = kk&63; segbase = 1500 + sf*512; seglen = 512; }
      int c = (kgl*4+s)*2;
      float v0=0.f, v1=0.f;
      if (o < 300 && c < seglen){
        v0 = w1[(size_t)o*2524 + segbase + c];
        if (c+1 < seglen) v1 = w1[(size_t)o*2524 + segbase + c + 1];
      }
      f16x2 t; t.x=(_Float16)v0; t.y=(_Float16)v1;
      W_14[idx] = t; continue;
    }
    idx -= N1;
    if (idx < N2){
      int kg = idx/(304*4);
      int rem = idx - kg*(304*4);
      int o = rem>>2, s = rem&3;
      int c = (kg*4+s)*2;
      float v0=0.f, v1=0.f;
      if (o < 300 && c < 300){ v0 = w2[(size_t)o*300+c]; v1 = w2[(size_t)o*300+c+1]; }
      f16x2 t; t.x=(_Float16)v0; t.y=(_Float16)v1;
      W_24[idx] = t; continue;
    }
    idx -= N2;
    syncc[idx] = 0;
  }
}

// ---------------------------------------------------------------------------
// H0 = relu(features @ w_in^T + b_in), coalesced fp16 weights.
// ---------------------------------------------------------------------------
__global__ __launch_bounds__(256) void h0_kernel(const float* __restrict__ feat,
    const f16x2* __restrict__ WH, const float* __restrict__ b_in, float* __restrict__ H0)
{
  const int tid = threadIdx.x;
  const int r0  = blockIdx.x*8;
  __shared__ f16x2 X[8][512];
  for (int t=tid; t<8*512; t+=256){
    int r=t>>9, p=t&511, c=2*p;
    f16x2 h; h.x=(_Float16)feat[(size_t)(r0+r)*1024+c];
    h.y=(_Float16)feat[(size_t)(r0+r)*1024+c+1];
    X[r][p]=h;
  }
  __syncthreads();
  const uint4* WHu = (const uint4*)WH;
  const int o0 = tid, o1 = tid+256;
  const bool h1v = (o1 < 300);
  float acc[2][8];
  #pragma unroll
  for (int j=0;j<2;j++)
    #pragma unroll
    for (int r=0;r<8;r++) acc[j][r]=0.f;
  for (int kg=0; kg<128; kg++){
    U w0, w1;
    w0.u = WHu[(size_t)kg*300 + o0];
    if (h1v) w1.u = WHu[(size_t)kg*300 + o1];
    #pragma unroll
    for (int r=0;r<8;r++){
      const f16x2* xp = &X[r][kg*4];
      f16x2 x0=xp[0],x1=xp[1],x2=xp[2],x3=xp[3];
      acc[0][r] = fdot2a(w0.h[3],x3, fdot2a(w0.h[2],x2, fdot2a(w0.h[1],x1, fdot2a(w0.h[0],x0, acc[0][r]))));
      if (h1v)
        acc[1][r] = fdot2a(w1.h[3],x3, fdot2a(w1.h[2],x2, fdot2a(w1.h[1],x1, fdot2a(w1.h[0],x0, acc[1][r]))));
    }
  }
  {
    float bb = b_in[o0];
    #pragma unroll
    for (int r=0;r<8;r++) H0[(size_t)(r0+r)*HID + o0] = fmaxf(acc[0][r]+bb, 0.f);
  }
  if (h1v){
    float bb = b_in[o1];
    #pragma unroll
    for (int r=0;r<8;r++) H0[(size_t)(r0+r)*HID + o1] = fmaxf(acc[1][r]+bb, 0.f);
  }
}

// ---------------------------------------------------------------------------
// Fused 4-layer pipelined scan, d-SPLIT paired WGs + WAVE SPECIALIZATION:
// waves 8-15 (tid>=512) stream P(i+1) in 4 register-resident chunks placed in
// the B/C/D/E phase slots of step i (pre_s/xh/xf parity double-buffered);
// waves 0-7 run {R(i+1) || import+kd+softmax} -> B -> C -> D -> E.
// Cross-layer producer lead raised to 2 steps (poll 2*(i+3)).
// ---------------------------------------------------------------------------
__global__ __launch_bounds__(1024) void scan_pipe_kernel(
  float* __restrict__ Hball,
  const f16x2* __restrict__ W_M4, const f16x2* __restrict__ WrT4, const f16x2* __restrict__ W_P4,
  const float* __restrict__ bih_c, const float* __restrict__ bhh_c,
  const float* __restrict__ bih_p, const float* __restrict__ bhh_p,
  const float* __restrict__ gwq, const float* __restrict__ gwk, const float* __restrict__ gbv,
  const int* __restrict__ speakers, float* __restrict__ xrow, int* __restrict__ syncc,
  float* __restrict__ xhEx)
{
  (void)gwq; (void)gbv;   // softmax is shift-invariant: q and b cancel exactly
  __shared__ _Float16 Hh[2][NSEQ][304];
  __shared__ float pre_s[2][2][1800];   // [parity][chain][1800]
  __shared__ float gates[2][1800];
  __shared__ float Mf[2][304];
  __shared__ f16x2 Mh[2][152];
  __shared__ f16x2 u01h[2][304];
  __shared__ float wgt[2][NSEQ];
  __shared__ float kd[2][NSEQ];
  __shared__ float red[2][320];
  __shared__ float xf[2][2][304];       // [parity][chain][304]
  __shared__ f16x2 xh[2][2][152];       // [parity][chain][152]
  __shared__ int   spk[2][NSEQ];
  __shared__ int   startA[2][NSEQ];
  __shared__ int   sLayer, sPair, sHalf;

  const int tid = threadIdx.x;

  // --- claim (layer, pair, half) with XCD-local preference; 64 slots/layer ---
  if (tid == 0){
    int xcc = 0;
    asm volatile("s_getreg_b32 %0, hwreg(HW_REG_XCC_ID)" : "=s"(xcc));
    int pref = (xcc >> 1) & 3;
    int* claimc = syncc + 3*32*16 + 3*128*2*16;
    int l = 0, p = 0, hfv = 0;
    #pragma unroll 1
    for (int t=0; t<4; ++t){
      int cand = (pref + t) & 3;
      int idx = __hip_atomic_fetch_add(&claimc[cand*16], 1, __ATOMIC_RELAXED, __HIP_MEMORY_SCOPE_AGENT);
      if (idx < 64){ l = cand; p = idx>>1; hfv = idx&1; break; }
    }
    sLayer = l; sPair = p; sHalf = hfv;
  }
  __syncthreads();
  const int layer = sLayer;
  const int pair  = sPair;
  const int hf    = sHalf;
  const int base0 = (2*pair)*NSEQ;
  const int base1 = (2*pair+1)*NSEQ;

  const uint4* Wm4 = (const uint4*)(W_M4 + (size_t)layer*38*1800*4);
  const uint4* Wr4 = (const uint4*)(WrT4 + (size_t)layer*38*600*4);
  const uint4* Wp4 = (const uint4*)(W_P4 + (size_t)layer*38*1800*4);
  const float* HinB0 = Hball + (size_t)base0*300;
  const float* HinB1 = Hball + (size_t)base1*300;
  float* HoutB0 = Hball + ((size_t)(layer+1)*NROWS + (size_t)base0)*300;
  float* HoutB1 = Hball + ((size_t)(layer+1)*NROWS + (size_t)base1)*300;
  int* cntP = syncc + (layer*32 + pair)*16;
  int* cntC = (layer>0) ? (syncc + ((layer-1)*32 + pair)*16) : (int*)0;
  const float* xin  = xrow + (size_t)(((layer-1)*32 + pair)*2)*NSEQ*300;  // layer>0
  float*       xout = xrow + (size_t)((layer*32 + pair)*2)*NSEQ*300;      // layer<3

  // h-exchange pointers: per half, 2 parity slots x (2 chains x 150) f32
  const int lp = layer*32 + pair;
  float* xhMy = xhEx + ((size_t)lp*2 + hf)*600;
  const float* xhPt = xhEx + ((size_t)lp*2 + (1-hf))*600;
  int* fEmy = syncc + 1536 + (lp*2 + hf)*16;
  const int* fEpt = syncc + 1536 + (lp*2 + (1-hf))*16;

  const int w    = tid >> 6;   // wave id 0..15
  const int lane = tid & 63;

  // ---- E mapping: chain0 = tid 0..149, chain1 = tid 256..405 ----
  int ec = -1, ert = 0;
  if (tid < 150){ ec = 0; ert = tid; }
  else if (tid >= 256 && tid < 406){ ec = 1; ert = tid - 256; }
  float bcr=0,bcz=0,bcn=0,bpr=0,bpz=0,bpn=0,wkv=0; int deE=0;
  if (ec >= 0){
    deE = hf*150 + ert;
    bcr=bhh_c[layer*900+deE]; bcz=bhh_c[layer*900+300+deE]; bcn=bhh_c[layer*900+600+deE];
    bpr=bih_p[layer*900+deE]; bpz=bih_p[layer*900+300+deE]; bpn=bih_p[layer*900+600+deE];
    wkv=gwk[layer*300+deE];
  }
  // ---- import regs (waves 0,1): partner gwk, 3 per lane ----
  float wkp0=0, wkp1=0, wkp2=0;
  if (w < 2){
    const int pbase = layer*300 + (1-hf)*150;
    wkp0 = gwk[pbase + lane];
    wkp1 = gwk[pbase + 64 + lane];
    if (lane < 22) wkp2 = gwk[pbase + 128 + lane];
  }
  // ---- D rows (serial waves): r1 = tid, r2 = tid+512 ----
  int opmD1 = 0, opmD2 = 0; bool hasD2 = false;
  if (tid < 512){
    { int g = tid/150; opmD1 = g*300 + hf*150 + (tid - g*150); }
    hasD2 = (tid < 388);
    if (hasD2){ int r2 = tid+512; int g = r2/150; opmD2 = g*300 + hf*150 + (r2 - g*150); }
  }
  // ---- P rows (P waves): q1 = tid-512, q2 = tid ----
  int opmP1 = 0, opmP2 = 0; bool hasP2 = false; float ppbP1 = 0.f, ppbP2 = 0.f;
  if (tid >= 512){
    int q1 = tid - 512;
    { int g = q1/150; opmP1 = g*300 + hf*150 + (q1 - g*150); }
    ppbP1 = (opmP1<900) ? bih_c[layer*900+opmP1] : bhh_p[layer*900+(opmP1-900)];
    hasP2 = (tid < 900);
    if (hasP2){
      int q2 = tid; int g = q2/150; opmP2 = g*300 + hf*150 + (q2 - g*150);
      ppbP2 = (opmP2<900) ? bih_c[layer*900+opmP2] : bhh_p[layer*900+(opmP2-900)];
    }
  }
  const bool hasC2 = (tid < 88);   // C second row r2 = tid+512 < 600

  // ---- init LDS ----
  if (tid < 64) spk[0][tid] = speakers[base0+tid];
  else if (tid < 128) spk[1][tid-64] = speakers[base1+(tid-64)];
  for (int t=tid; t<2*1800; t+=1024) ((float*)gates)[t]=0.f;
  for (int t=tid; t<2*304; t+=1024) ((float*)Mf)[t]=0.f;
  if (tid >= 128 && tid < 168){ int t=tid-128; red[t/20][300+(t%20)] = 0.f; }
  if (tid >= 168 && tid < 176){
    int t=tid-168; f16x2 z; z.x=(_Float16)0.f; z.y=(_Float16)0.f;
    xh[t&1][(t>>1)&1][150+((t>>2)&1)] = z;   // both parities, both chains, both pad slots
  }
  if (tid >= 176 && tid < 180){
    int t=tid-176; f16x2 z; z.x=(_Float16)0.f; z.y=(_Float16)0.f;
    Mh[t>>1][150+(t&1)]=z;
    u01h[t>>1][150+(t&1)]=z; u01h[t>>1][302+(t&1)]=z;
  }
  __syncthreads();
  if (tid < 64){
    int s=0; for (int j=tid-1;j>=0;--j) if (spk[0][j]==spk[0][tid]){s=j;break;}
    startA[0][tid]=s;
  } else if (tid < 128){
    int t=tid-64;
    int s=0; for (int j=t-1;j>=0;--j) if (spk[1][j]==spk[1][t]){s=j;break;}
    startA[1][t]=s;
  }
  // producer must have finished steps 0 and 1 (R(0) + step0's R(1))
  if (layer>0 && tid==0){
    while (xloadi(cntC) < 4) __builtin_amdgcn_s_sleep(8);
  }
  __syncthreads();

  // ---- prologue R(0) -> parity 0 ----
  {
    int rcR=-1, rtR=0;
    if (tid>=128 && tid<278){ rcR=0; rtR=tid-128; }
    else if (tid>=288 && tid<438){ rcR=1; rtR=tid-288; }
    if (rcR >= 0){
      float x0, x1;
      if (layer==0){
        const float* Hin = rcR ? HinB1 : HinB0;
        float2 v = *(const float2*)(Hin + 2*rtR);
        x0=v.x; x1=v.y;
      } else {
        const float* xi = xin + (size_t)rcR*NSEQ*300;
        x0 = xload(xi + 2*rtR);
        x1 = xload(xi + 2*rtR + 1);
      }
      xf[0][rcR][2*rtR]=x0; xf[0][rcR][2*rtR+1]=x1;
      f16x2 h; h.x=(_Float16)x0; h.y=(_Float16)x1; xh[0][rcR][rtR]=h;
    }
  }
  __syncthreads();
  // ---- prologue P(0) -> pre_s[0] ----
  if (tid >= 512){
    const int np = 0;
    float p1a0=0,p1a1=0,p1a2=0,p1a3=0,p1b0=0,p1b1=0,p1b2=0,p1b3=0;
    float p2a0=0,p2a1=0,p2a2=0,p2a3=0,p2b0=0,p2b1=0,p2b2=0,p2b3=0;
    PCH(0,38)
    pre_s[np][0][opmP1] = (p1a0+p1a1)+(p1a2+p1a3) + ppbP1;
    pre_s[np][1][opmP1] = (p1b0+p1b1)+(p1b2+p1b3) + ppbP1;
    if (hasP2){
      pre_s[np][0][opmP2] = (p2a0+p2a1)+(p2a2+p2a3) + ppbP2;
      pre_s[np][1][opmP2] = (p2b0+p2b1)+(p2b2+p2b3) + ppbP2;
    }
  }
  __syncthreads();

  for (int i=0; i<NSEQ; ++i){
    const int cur = i&1, np = cur^1;
    // P(i+1) chunk accumulators (live across the step's phase slots)
    float p1a0=0,p1a1=0,p1a2=0,p1a3=0,p1b0=0,p1b1=0,p1b2=0,p1b3=0;
    float p2a0=0,p2a1=0,p2a2=0,p2a3=0,p2b0=0,p2b1=0,p2b2=0,p2b3=0;

    // ---- ph1: R(i+1) on tid 128-437  ||  import+kd+softmax on waves 0,1 ----
    if (i < 63){
      int rcR=-1, rtR=0;
      if (tid>=128 && tid<278){ rcR=0; rtR=tid-128; }
      else if (tid>=288 && tid<438){ rcR=1; rtR=tid-288; }
      if (rcR >= 0){
        float x0, x1;
        if (layer==0){
          const float* Hin = rcR ? HinB1 : HinB0;
          float2 v = *(const float2*)(Hin + (size_t)(i+1)*300 + 2*rtR);
          x0=v.x; x1=v.y;
        } else {
          const float* xi = xin + (size_t)rcR*NSEQ*300 + (size_t)(i+1)*300;
          x0 = xload(xi + 2*rtR);
          x1 = xload(xi + 2*rtR + 1);
        }
        xf[np][rcR][2*rtR]=x0; xf[np][rcR][2*rtR+1]=x1;
        f16x2 h; h.x=(_Float16)x0; h.y=(_Float16)x1; xh[np][rcR][rtR]=h;
      }
    }
    if (w < 2 && i > 0){
      const int c = w;
      while (xloadi(fEpt) < i) __builtin_amdgcn_s_sleep(1);
      const int par = ((i-1)&1)*300 + c*150;
      const int pb = (1-hf)*150;
      float hv0 = xload(xhPt + par + lane);
      float hv1 = xload(xhPt + par + 64 + lane);
      float hv2 = (lane<22) ? xload(xhPt + par + 128 + lane) : 0.f;
      red[c][pb+lane] = hv0*wkp0;      Hh[c][i-1][pb+lane] = (_Float16)hv0;
      red[c][pb+64+lane] = hv1*wkp1;   Hh[c][i-1][pb+64+lane] = (_Float16)hv1;
      if (lane<22){ red[c][pb+128+lane] = hv2*wkp2; Hh[c][i-1][pb+128+lane] = (_Float16)hv2; }
      float s = red[c][lane]+red[c][lane+64]+red[c][lane+128]+red[c][lane+192]+red[c][lane+256];
      #pragma unroll
      for (int o=32;o>0;o>>=1) s += __shfl_xor(s,o);
      if (lane==0) kd[c][i-1]=s;
      {
        const int st = startA[c][i];
        const bool in = (lane>=st) && (lane<i);
        float kv = (lane==i-1) ? s : kd[c][lane];
        float a = in ? kv : -3.0e38f;
        float m = a;
        #pragma unroll
        for (int o=32;o>0;o>>=1) m = fmaxf(m,__shfl_xor(m,o));
        float e = in ? __expf(a-m) : 0.f;
        float ss = e;
        #pragma unroll
        for (int o=32;o>0;o>>=1) ss += __shfl_xor(ss,o);
        wgt[c][lane] = e/ss;
      }
    }
    __syncthreads();                                        // bar1

    // ---- ph2: B (serial)  ||  P chunk 0 ----
    if (tid < 512){
      if (i > 0){
        #pragma unroll 1
        for (int pass=0; pass<3; ++pass){
          int T = tid + pass*512;
          if (T < 1200){
            const int c = (T >= 600);
            const int t = T - c*600;
            const int d  = (t<300)? t : (t-300);
            const int wh = (t>=300);
            const int st = startA[c][i]; const int ms = spk[c][i];
            float u=0.f;
            for (int j=st;j<i;++j){
              float sel = ((spk[c][j]==ms) != (wh!=0)) ? 1.f : 0.f;
              u += sel*wgt[c][j]*(float)Hh[c][j][d];
            }
            ((_Float16*)&u01h[c][0])[(wh?304:0) + d] = (_Float16)u;
          }
        }
      }
    } else if (i < 63){
      PCH(0,10)
    }
    __syncthreads();                                        // bar2

    // ---- ph3: C (serial, dual-row)  ||  P chunk 1 ----
    if (tid < 512){
      if (i > 0){
        const int hh = tid&1;
        const f16x2* uA = (const f16x2*)&u01h[0][0] + hh*152;
        const f16x2* uB = (const f16x2*)&u01h[1][0] + hh*152;
        float a0=0,a1=0,a2=0,a3=0, b0=0,b1=0,b2=0,b3=0;
        float e0=0,e1=0,e2=0,e3=0, f0=0,f1=0,f2=0,f3=0;
        for (int kg=0;kg<38;kg++){
          U v1; v1.u = Wr4[(size_t)kg*600 + tid];
          U v2; if (hasC2) v2.u = Wr4[(size_t)kg*600 + tid + 512];
          f16x2 uA0=uA[kg*4+0],uA1=uA[kg*4+1],uA2=uA[kg*4+2],uA3=uA[kg*4+3];
          f16x2 uB0=uB[kg*4+0],uB1=uB[kg*4+1],uB2=uB[kg*4+2],uB3=uB[kg*4+3];
          a0=fdot2a(v1.h[0],uA0,a0); a1=fdot2a(v1.h[1],uA1,a1);
          a2=fdot2a(v1.h[2],uA2,a2); a3=fdot2a(v1.h[3],uA3,a3);
          b0=fdot2a(v1.h[0],uB0,b0); b1=fdot2a(v1.h[1],uB1,b1);
          b2=fdot2a(v1.h[2],uB2,b2); b3=fdot2a(v1.h[3],uB3,b3);
          if (hasC2){
            e0=fdot2a(v2.h[0],uA0,e0); e1=fdot2a(v2.h[1],uA1,e1);
            e2=fdot2a(v2.h[2],uA2,e2); e3=fdot2a(v2.h[3],uA3,e3);
            f0=fdot2a(v2.h[0],uB0,f0); f1=fdot2a(v2.h[1],uB1,f1);
            f2=fdot2a(v2.h[2],uB2,f2); f3=fdot2a(v2.h[3],uB3,f3);
          }
        }
        float aA = (a0+a1)+(a2+a3);
        float aB = (b0+b1)+(b2+b3);
        float m2A = aA + __shfl_xor(aA,1);
        float m2B = aB + __shfl_xor(aB,1);
        if ((tid&1)==0){ Mf[0][tid>>1] = m2A; Mf[1][tid>>1] = m2B; }
        float moA = __shfl_xor(m2A,2);
        float moB = __shfl_xor(m2B,2);
        if ((tid&3)==0){
          f16x2 hA; hA.x=(_Float16)m2A; hA.y=(_Float16)moA; Mh[0][tid>>2]=hA;
          f16x2 hB; hB.x=(_Float16)m2B; hB.y=(_Float16)moB; Mh[1][tid>>2]=hB;
        }
        if (hasC2){
          const int r2 = tid + 512;
          float cA = (e0+e1)+(e2+e3);
          float cB = (f0+f1)+(f2+f3);
          float n2A = cA + __shfl_xor(cA,1);
          float n2B = cB + __shfl_xor(cB,1);
          if ((tid&1)==0){ Mf[0][r2>>1] = n2A; Mf[1][r2>>1] = n2B; }
          float noA = __shfl_xor(n2A,2);
          float noB = __shfl_xor(n2B,2);
          if ((tid&3)==0){
            f16x2 hA; hA.x=(_Float16)n2A; hA.y=(_Float16)noA; Mh[0][r2>>2]=hA;
            f16x2 hB; hB.x=(_Float16)n2B; hB.y=(_Float16)noB; Mh[1][r2>>2]=hB;
          }
        }
      }
    } else if (i < 63){
      PCH(10,20)
    }
    __syncthreads();                                        // bar3

    // ---- ph4: D (serial, dual-row)  ||  P chunk 2 ----
    if (tid < 512){
      if (i > 0){
        float a0=0,a1=0,a2=0,a3=0, b0=0,b1=0,b2=0,b3=0;
        float e0=0,e1=0,e2=0,e3=0, f0=0,f1=0,f2=0,f3=0;
        for (int kg=0;kg<38;kg++){
          U v1; v1.u = Wm4[(size_t)kg*1800 + opmD1];
          U v2; if (hasD2) v2.u = Wm4[(size_t)kg*1800 + opmD2];
          f16x2 mA0=Mh[0][kg*4+0], mA1=Mh[0][kg*4+1], mA2=Mh[0][kg*4+2], mA3=Mh[0][kg*4+3];
          f16x2 mB0=Mh[1][kg*4+0], mB1=Mh[1][kg*4+1], mB2=Mh[1][kg*4+2], mB3=Mh[1][kg*4+3];
          a0=fdot2a(v1.h[0],mA0,a0); a1=fdot2a(v1.h[1],mA1,a1);
          a2=fdot2a(v1.h[2],mA2,a2); a3=fdot2a(v1.h[3],mA3,a3);
          b0=fdot2a(v1.h[0],mB0,b0); b1=fdot2a(v1.h[1],mB1,b1);
          b2=fdot2a(v1.h[2],mB2,b2); b3=fdot2a(v1.h[3],mB3,b3);
          if (hasD2){
            e0=fdot2a(v2.h[0],mA0,e0); e1=fdot2a(v2.h[1],mA1,e1);
            e2=fdot2a(v2.h[2],mA2,e2); e3=fdot2a(v2.h[3],mA3,e3);
            f0=fdot2a(v2.h[0],mB0,f0); f1=fdot2a(v2.h[1],mB1,f1);
            f2=fdot2a(v2.h[2],mB2,f2); f3=fdot2a(v2.h[3],mB3,f3);
          }
        }
        gates[0][opmD1] = (a0+a1)+(a2+a3);
        gates[1][opmD1] = (b0+b1)+(b2+b3);
        if (hasD2){
          gates[0][opmD2] = (e0+e1)+(e2+e3);
          gates[1][opmD2] = (f0+f1)+(f2+f3);
        }
      }
    } else if (i < 63){
      PCH(20,29)
    }
    __syncthreads();                                        // bar4

    // ---- ph5: E (serial)  ||  P chunk 3 + pre_s[np] write ----
    if (ec >= 0){
      const int de = deE;
      const float M = Mf[ec][de];
      const float* ps = pre_s[cur][ec];
      const float* gs = gates[ec];
      float r  = sigm(ps[de] + gs[de] + bcr);
      float z  = sigm(ps[300+de] + gs[300+de] + bcz);
      float n  = tanhf(ps[600+de] + r*(gs[600+de]+bcn));
      float C  = (1.f-z)*n + z*M;
      float rp = sigm(gs[900+de]+bpr + ps[900+de]);
      float zp = sigm(gs[1200+de]+bpz + ps[1200+de]);
      float np_ = tanhf(gs[1500+de]+bpn + rp*ps[1500+de]);
      float qv = xf[cur][ec][de];
      float P  = (1.f-zp)*np_ + zp*qv;
      float h  = C + P;
      Hh[ec][i][de] = (_Float16)h;
      red[ec][de] = h*wkv;
      float* Ho = ec ? HoutB1 : HoutB0;
      Ho[(size_t)i*300 + de] = h;
      xstore(xhMy + (i&1)*300 + ec*150 + ert, h);
      if (layer<3) xstore(xout + (size_t)ec*NSEQ*300 + (size_t)i*300 + de, h);
    }
    if (tid >= 512 && i < 63){
      PCH(29,38)
      pre_s[np][0][opmP1] = (p1a0+p1a1)+(p1a2+p1a3) + ppbP1;
      pre_s[np][1][opmP1] = (p1b0+p1b1)+(p1b2+p1b3) + ppbP1;
      if (hasP2){
        pre_s[np][0][opmP2] = (p2a0+p2a1)+(p2a2+p2a3) + ppbP2;
        pre_s[np][1][opmP2] = (p2b0+p2b1)+(p2b2+p2b3) + ppbP2;
      }
    }
    asm volatile("s_waitcnt vmcnt(0)" ::: "memory");   // drain publish before flags
    __syncthreads();                                        // bar5
    if (tid==0){
      __hip_atomic_fetch_add(fEmy, 1, __ATOMIC_RELAXED, __HIP_MEMORY_SCOPE_AGENT);
      if (layer<3) __hip_atomic_fetch_add(cntP, 1, __ATOMIC_RELAXED, __HIP_MEMORY_SCOPE_AGENT);
      if (layer>0 && i<62){
        while (xloadi(cntC) < 2*(i+3)) __builtin_amdgcn_s_sleep(8);
      }
    }
    __syncthreads();                                        // bar6
  }
}

// ---------------------------------------------------------------------------
// Head with fp16-dot2 GEMMs (unchanged).
// ---------------------------------------------------------------------------
__global__ __launch_bounds__(256) void head_kernel(
  const float* __restrict__ H0, const float* __restrict__ Hl1,
  const float* __restrict__ Hl2, const float* __restrict__ Hl3,
  const float* __restrict__ Hl4, const float* __restrict__ feat,
  const f16x2* __restrict__ W14, const float* __restrict__ b1,
  const f16x2* __restrict__ W24, const float* __restrict__ b2,
  const float* __restrict__ w3, const float* __restrict__ b3,
  float* __restrict__ out)
{
  const int tid = threadIdx.x;
  const int r0  = blockIdx.x*16;
  __shared__ f16x2 Xh[16*256];
  __shared__ _Float16 h1h[16*304];
  __shared__ float S2[16*304];
  const uint4* W14u = (const uint4*)W14;
  const uint4* W24u = (const uint4*)W24;

  float acc0[16], acc1[16];
  #pragma unroll
  for (int r=0;r<16;r++){ acc0[r]=0.f; acc1[r]=0.f; }
  const int o  = tid;
  const int o2 = tid + 256;
  const bool has2 = (o2 < 300);

  #pragma unroll
  for (int seg=0; seg<7; seg++){
    const float* src = (seg==0)?H0:(seg==1)?Hl1:(seg==2)?Hl2:(seg==3)?Hl3:(seg==4)?Hl4:feat;
    if (seg < 5){
      for (int t=tid; t<16*152; t+=256){
        int r=t/152, p=t-r*152, c=2*p;
        float v0 = (c<300)? src[(size_t)(r0+r)*300 + c] : 0.f;
        float v1 = (c+1<300)? src[(size_t)(r0+r)*300 + c+1] : 0.f;
        f16x2 h; h.x=(_Float16)v0; h.y=(_Float16)v1;
        Xh[r*256+p] = h;
      }
    } else {
      const int cb = (seg-5)*512;
      for (int t=tid; t<16*256; t+=256){
        int r=t>>8, p=t&255;
        float v0 = src[(size_t)(r0+r)*1024 + cb + 2*p];
        float v1 = src[(size_t)(r0+r)*1024 + cb + 2*p+1];
        f16x2 h; h.x=(_Float16)v0; h.y=(_Float16)v1;
        Xh[r*256+p] = h;
      }
    }
    __syncthreads();
    const int kgs = (seg<5)?38:64;
    const int kgo = (seg<5)? seg*38 : 190+(seg-5)*64;
    if (o < 300){
      for (int kg=0; kg<kgs; kg++){
        U a, b;
        a.u = W14u[(size_t)(kgo+kg)*304 + o];
        if (has2) b.u = W14u[(size_t)(kgo+kg)*304 + o2];
        #pragma unroll
        for (int r=0;r<16;r++){
          const f16x2* xp = &Xh[r*256 + kg*4];
          float t0 = fdot2a(a.h[0], xp[0], 0.f);
          t0 = fdot2a(a.h[1], xp[1], t0);
          t0 = fdot2a(a.h[2], xp[2], t0);
          t0 = fdot2a(a.h[3], xp[3], t0);
          acc0[r] += t0;
          if (has2){
            float t1 = fdot2a(b.h[0], xp[0], 0.f);
            t1 = fdot2a(b.h[1], xp[1], t1);
            t1 = fdot2a(b.h[2], xp[2], t1);
            t1 = fdot2a(b.h[3], xp[3], t1);
            acc1[r] += t1;
          }
        }
      }
    }
    __syncthreads();
  }
  if (o < 300){
    float bb = b1[o];
    #pragma unroll
    for (int r=0;r<16;r++) h1h[r*304+o] = (_Float16)fmaxf(acc0[r]+bb, 0.f);
  }
  if (has2){
    float bb = b1[o2];
    #pragma unroll
    for (int r=0;r<16;r++) h1h[r*304+o2] = (_Float16)fmaxf(acc1[r]+bb, 0.f);
  }
  if (tid < 4){
    #pragma unroll
    for (int r=0;r<16;r++) h1h[r*304+300+tid] = (_Float16)0.f;
  }
  __syncthreads();
  #pragma unroll
  for (int r=0;r<16;r++){ acc0[r]=0.f; acc1[r]=0.f; }
  if (o < 300){
    for (int kg=0; kg<38; kg++){
      U a, b;
      a.u = W24u[(size_t)kg*304 + o];
      if (has2) b.u = W24u[(size_t)kg*304 + o2];
      #pragma unroll
      for (int r=0;r<16;r++){
        const f16x2* xp = (const f16x2*)&h1h[r*304] + kg*4;
        float t0 = fdot2a(a.h[0], xp[0], 0.f);
        t0 = fdot2a(a.h[1], xp[1], t0);
        t0 = fdot2a(a.h[2], xp[2], t0);
        t0 = fdot2a(a.h[3], xp[3], t0);
        acc0[r] += t0;
        if (has2){
          float t1 = fdot2a(b.h[0], xp[0], 0.f);
          t1 = fdot2a(b.h[1], xp[1], t1);
          t1 = fdot2a(b.h[2], xp[2], t1);
          t1 = fdot2a(b.h[3], xp[3], t1);
          acc1[r] += t1;
        }
      }
    }
  }
  __syncthreads();
  if (o < 300){
    float bb = b2[o];
    #pragma unroll
    for (int r=0;r<16;r++) S2[r*304+o] = fmaxf(acc0[r]+bb, 0.f);
  }
  if (has2){
    float bb = b2[o2];
    #pragma unroll
    for (int r=0;r<16;r++) S2[r*304+o2] = fmaxf(acc1[r]+bb, 0.f);
  }
  __syncthreads();
  if (tid < 16*7){
    int r = tid/7, c = tid - r*7;
    float s = b3[c];
    const float* wrow = w3 + (size_t)c*HID;
    for (int k=0;k<300;k++) s += wrow[k]*S2[r*304+k];
    out[(size_t)(r0+r)*7 + c] = s;
  }
}

// ---------------------------------------------------------------------------
extern "C" void kernel_launch(void* const* d_in, const int* in_sizes, int n_in,
                              void* d_out, int out_size, void* d_ws, size_t ws_size,
                              hipStream_t stream)
{
  (void)in_sizes; (void)n_in; (void)out_size; (void)ws_size;
  const float* feat  = (const float*)d_in[0];
  const int*   spk   = (const int*)d_in[1];
  const float* w_in  = (const float*)d_in[2];
  const float* b_in  = (const float*)d_in[3];
  const float* gwq   = (const float*)d_in[4];
  const float* gwk   = (const float*)d_in[5];
  const float* gb    = (const float*)d_in[6];
  const float* wr0   = (const float*)d_in[7];
  const float* wr1   = (const float*)d_in[8];
  const float* wih_c = (const float*)d_in[9];
  const float* whh_c = (const float*)d_in[10];
  const float* bih_c = (const float*)d_in[11];
  const float* bhh_c = (const float*)d_in[12];
  const float* wih_p = (const float*)d_in[13];
  const float* whh_p = (const float*)d_in[14];
  const float* bih_p = (const float*)d_in[15];
  const float* bhh_p = (const float*)d_in[16];
  const float* w1    = (const float*)d_in[17];
  const float* b1    = (const float*)d_in[18];
  const float* w2    = (const float*)d_in[19];
  const float* b2    = (const float*)d_in[20];
  const float* w3    = (const float*)d_in[21];
  const float* b3    = (const float*)d_in[22];
  float* out = (float*)d_out;

  char* ws = (char*)d_ws;
  size_t off = 0;
  auto alloc = [&](size_t bytes)->void*{
    void* p = ws + off;
    off += (bytes + 255) & ~(size_t)255;
    return p;
  };
  f16x2* W_M4 = (f16x2*)alloc((size_t)4*38*1800*4 * sizeof(f16x2));
  f16x2* WrT4 = (f16x2*)alloc((size_t)4*38*600*4  * sizeof(f16x2));
  f16x2* W_P4 = (f16x2*)alloc((size_t)4*38*1800*4 * sizeof(f16x2));
  f16x2* W_H4 = (f16x2*)alloc((size_t)128*300*4   * sizeof(f16x2));
  f16x2* W_14 = (f16x2*)alloc((size_t)318*304*4   * sizeof(f16x2));
  f16x2* W_24 = (f16x2*)alloc((size_t)38*304*4    * sizeof(f16x2));
  float* Hball = (float*)alloc((size_t)5*NROWS*HID*sizeof(float));
  float* xrow  = (float*)alloc((size_t)3*64*NSEQ*HID*sizeof(float));
  int*   syncc = (int*)alloc((size_t)NSYNC*sizeof(int));
  float* xhEx  = (float*)alloc((size_t)128*2*600*sizeof(float));

  {
    const int tot = 4*38*1800*4 + 4*38*600*4 + 4*38*1800*4 + 128*300*4
                  + 318*304*4 + 38*304*4 + NSYNC;
    convert_all_kernel<<<(tot+255)/256, 256, 0, stream>>>(whh_c, wih_p, wih_c, whh_p,
        wr0, wr1, w_in, w1, w2, W_M4, WrT4, W_P4, W_H4, W_14, W_24, syncc);
  }
  h0_kernel<<<NROWS/8, 256, 0, stream>>>(feat, W_H4, b_in, Hball);

  scan_pipe_kernel<<<256, 1024, 0, stream>>>(Hball, W_M4, WrT4, W_P4,
      bih_c, bhh_c, bih_p, bhh_p, gwq, gwk, gb, spk, xrow, syncc, xhEx);

  head_kernel<<<NROWS/16, 256, 0, stream>>>(
      Hball, Hball + (size_t)NROWS*HID, Hball + (size_t)2*NROWS*HID,
      Hball + (size_t)3*NROWS*HID, Hball + (size_t)4*NROWS*HID,
      feat, W_14, b1, W_24, b2, w3, b3, out);
}

// Round 8
// 7889.150 us; speedup vs baseline: 1.0056x; 1.0056x over previous
//
#include <hip/hip_runtime.h>
#include <hip/hip_bf16.h>

typedef _Float16 f16x2 __attribute__((ext_vector_type(2)));

#define HID 300
#define NSEQ 64
#define NROWS 4096   // B*N = 64*64

union U { uint4 u; f16x2 h[4]; };

__device__ __forceinline__ float sigm(float x){ return 1.f/(1.f+__expf(-x)); }

__device__ __forceinline__ float fdot2a(f16x2 a, f16x2 b, float c){
#if __has_builtin(__builtin_amdgcn_fdot2)
  return __builtin_amdgcn_fdot2(a, b, c, false);
#else
  return c + (float)a.x*(float)b.x + (float)a.y*(float)b.y;
#endif
}

// Relaxed agent-scope ops: LLC-coherent, NO cache maintenance (no L2 flush).
__device__ __forceinline__ void xstore(float* p, float v){
  __hip_atomic_store(p, v, __ATOMIC_RELAXED, __HIP_MEMORY_SCOPE_AGENT);
}
__device__ __forceinline__ float xload(const float* p){
  return __hip_atomic_load(p, __ATOMIC_RELAXED, __HIP_MEMORY_SCOPE_AGENT);
}
__device__ __forceinline__ int xloadi(const int* p){
  return __hip_atomic_load(p, __ATOMIC_RELAXED, __HIP_MEMORY_SCOPE_AGENT);
}

// sync area layout (ints):
//   [0, 1536)            : cross-layer step counters (3 layers x 32 pairs x 16)
//   [1536, 1536+4096)    : fE flags (h-exchange, 128 pairs x 2 halves x 16)
//   [13824, 13824+64)    : claim pools (4 layers x 16)   (gap kept zeroed)
#define NSYNC (3*32*16 + 3*128*2*16 + 64)

// P-chunk: rows opmP1/opmP2 of Wp against xh[np], accumulating in 16 scalars.
#define PCH(K0,K1) \
  for (int kg=(K0); kg<(K1); ++kg){ \
    U v1; v1.u = Wp4[(size_t)kg*1800 + opmP1]; \
    U v2; if (hasP2) v2.u = Wp4[(size_t)kg*1800 + opmP2]; \
    f16x2 xA0=xh[np][0][kg*4+0],xA1=xh[np][0][kg*4+1],xA2=xh[np][0][kg*4+2],xA3=xh[np][0][kg*4+3]; \
    f16x2 xB0=xh[np][1][kg*4+0],xB1=xh[np][1][kg*4+1],xB2=xh[np][1][kg*4+2],xB3=xh[np][1][kg*4+3]; \
    p1a0=fdot2a(v1.h[0],xA0,p1a0); p1a1=fdot2a(v1.h[1],xA1,p1a1); \
    p1a2=fdot2a(v1.h[2],xA2,p1a2); p1a3=fdot2a(v1.h[3],xA3,p1a3); \
    p1b0=fdot2a(v1.h[0],xB0,p1b0); p1b1=fdot2a(v1.h[1],xB1,p1b1); \
    p1b2=fdot2a(v1.h[2],xB2,p1b2); p1b3=fdot2a(v1.h[3],xB3,p1b3); \
    if (hasP2){ \
      p2a0=fdot2a(v2.h[0],xA0,p2a0); p2a1=fdot2a(v2.h[1],xA1,p2a1); \
      p2a2=fdot2a(v2.h[2],xA2,p2a2); p2a3=fdot2a(v2.h[3],xA3,p2a3); \
      p2b0=fdot2a(v2.h[0],xB0,p2b0); p2b1=fdot2a(v2.h[1],xB1,p2b1); \
      p2b2=fdot2a(v2.h[2],xB2,p2b2); p2b3=fdot2a(v2.h[3],xB3,p2b3); \
    } \
  }

// ---------------------------------------------------------------------------
// Merged repack: f32 -> fp16 pairs, [kg][outs][4 pairs] coalesced; also zeroes
// the pipeline sync counters + claim pools every launch.
// ---------------------------------------------------------------------------
__global__ void convert_all_kernel(
    const float* __restrict__ whh_c, const float* __restrict__ wih_p,
    const float* __restrict__ wih_c, const float* __restrict__ whh_p,
    const float* __restrict__ wr0,   const float* __restrict__ wr1,
    const float* __restrict__ w_in,  const float* __restrict__ w1,
    const float* __restrict__ w2,
    f16x2* __restrict__ W_M4, f16x2* __restrict__ WrT4, f16x2* __restrict__ W_P4,
    f16x2* __restrict__ W_H4, f16x2* __restrict__ W_14, f16x2* __restrict__ W_24,
    int* __restrict__ syncc)
{
  const int NA = 4*38*1800*4;
  const int NB = 4*38*600*4;
  const int NP = 4*38*1800*4;
  const int NH = 128*300*4;
  const int N1 = 318*304*4;
  const int N2 = 38*304*4;
  const int NS = NSYNC;
  const int TOT = NA+NB+NP+NH+N1+N2+NS;
  for (int idx0 = blockIdx.x*blockDim.x + threadIdx.x; idx0 < TOT; idx0 += gridDim.x*blockDim.x){
    int idx = idx0;
    if (idx < NA){
      int l    = idx/(38*1800*4);
      int rem  = idx - l*(38*1800*4);
      int kg   = rem/(1800*4);
      int rem2 = rem - kg*(1800*4);
      int o = rem2>>2, s = rem2&3;
      int c = (kg*4+s)*2;
      float v0=0.f, v1=0.f;
      if (c < 300){
        const float* src = (o<900) ? (whh_c + ((size_t)l*900+o)*300)
                                   : (wih_p + ((size_t)l*900+(o-900))*300);
        v0 = src[c]; v1 = src[c+1];
      }
      f16x2 t; t.x=(_Float16)v0; t.y=(_Float16)v1;
      W_M4[idx] = t; continue;
    }
    idx -= NA;
    if (idx < NB){
      int l    = idx/(38*600*4);
      int rem  = idx - l*(38*600*4);
      int kg   = rem/(600*4);
      int rem2 = rem - kg*(600*4);
      int t6 = rem2>>2, s = rem2&3;
      int d = t6>>1, hh = t6&1;
      int c = (kg*4+s)*2;
      float v0=0.f, v1=0.f;
      if (c < 300){
        const float* src = hh ? (wr1 + ((size_t)l*300+d)*300)
                              : (wr0 + ((size_t)l*300+d)*300);
        v0 = src[c]; v1 = src[c+1];
      }
      f16x2 t; t.x=(_Float16)v0; t.y=(_Float16)v1;
      WrT4[idx] = t; continue;
    }
    idx -= NB;
    if (idx < NP){
      int l    = idx/(38*1800*4);
      int rem  = idx - l*(38*1800*4);
      int kg   = rem/(1800*4);
      int rem2 = rem - kg*(1800*4);
      int o = rem2>>2, s = rem2&3;
      int c = (kg*4+s)*2;
      float v0=0.f, v1=0.f;
      if (c < 300){
        const float* src = (o<900) ? (wih_c + ((size_t)l*900+o)*300)
                                   : (whh_p + ((size_t)l*900+(o-900))*300);
        v0 = src[c]; v1 = src[c+1];
      }
      f16x2 t; t.x=(_Float16)v0; t.y=(_Float16)v1;
      W_P4[idx] = t; continue;
    }
    idx -= NP;
    if (idx < NH){
      int kg  = idx/(300*4);
      int rem = idx - kg*(300*4);
      int o = rem>>2, s = rem&3;
      int c = (kg*4+s)*2;
      f16x2 t; t.x=(_Float16)w_in[(size_t)o*1024+c]; t.y=(_Float16)w_in[(size_t)o*1024+c+1];
      W_H4[idx] = t; continue;
    }
    idx -= NH;
    if (idx < N1){
      int kgg = idx/(304*4);
      int rem = idx - kgg*(304*4);
      int o = rem>>2, s = rem&3;
      int segbase, seglen, kgl;
      if (kgg < 190){ int seg = kgg/38; kgl = kgg - seg*38; segbase = seg*300; seglen = 300; }
      else { int kk = kgg-190; int sf = kk>>6; kgl = kk&63; segbase = 1500 + sf*512; seglen = 512; }
      int c = (kgl*4+s)*2;
      float v0=0.f, v1=0.f;
      if (o < 300 && c < seglen){
        v0 = w1[(size_t)o*2524 + segbase + c];
        if (c+1 < seglen) v1 = w1[(size_t)o*2524 + segbase + c + 1];
      }
      f16x2 t; t.x=(_Float16)v0; t.y=(_Float16)v1;
      W_14[idx] = t; continue;
    }
    idx -= N1;
    if (idx < N2){
      int kg = idx/(304*4);
      int rem = idx - kg*(304*4);
      int o = rem>>2, s = rem&3;
      int c = (kg*4+s)*2;
      float v0=0.f, v1=0.f;
      if (o < 300 && c < 300){ v0 = w2[(size_t)o*300+c]; v1 = w2[(size_t)o*300+c+1]; }
      f16x2 t; t.x=(_Float16)v0; t.y=(_Float16)v1;
      W_24[idx] = t; continue;
    }
    idx -= N2;
    syncc[idx] = 0;
  }
}

// ---------------------------------------------------------------------------
// H0 = relu(features @ w_in^T + b_in), coalesced fp16 weights.
// ---------------------------------------------------------------------------
__global__ __launch_bounds__(256) void h0_kernel(const float* __restrict__ feat,
    const f16x2* __restrict__ WH, const float* __restrict__ b_in, float* __restrict__ H0)
{
  const int tid = threadIdx.x;
  const int r0  = blockIdx.x*8;
  __shared__ f16x2 X[8][512];
  for (int t=tid; t<8*512; t+=256){
    int r=t>>9, p=t&511, c=2*p;
    f16x2 h; h.x=(_Float16)feat[(size_t)(r0+r)*1024+c];
    h.y=(_Float16)feat[(size_t)(r0+r)*1024+c+1];
    X[r][p]=h;
  }
  __syncthreads();
  const uint4* WHu = (const uint4*)WH;
  const int o0 = tid, o1 = tid+256;
  const bool h1v = (o1 < 300);
  float acc[2][8];
  #pragma unroll
  for (int j=0;j<2;j++)
    #pragma unroll
    for (int r=0;r<8;r++) acc[j][r]=0.f;
  for (int kg=0; kg<128; kg++){
    U w0, w1;
    w0.u = WHu[(size_t)kg*300 + o0];
    if (h1v) w1.u = WHu[(size_t)kg*300 + o1];
    #pragma unroll
    for (int r=0;r<8;r++){
      const f16x2* xp = &X[r][kg*4];
      f16x2 x0=xp[0],x1=xp[1],x2=xp[2],x3=xp[3];
      acc[0][r] = fdot2a(w0.h[3],x3, fdot2a(w0.h[2],x2, fdot2a(w0.h[1],x1, fdot2a(w0.h[0],x0, acc[0][r]))));
      if (h1v)
        acc[1][r] = fdot2a(w1.h[3],x3, fdot2a(w1.h[2],x2, fdot2a(w1.h[1],x1, fdot2a(w1.h[0],x0, acc[1][r]))));
    }
  }
  {
    float bb = b_in[o0];
    #pragma unroll
    for (int r=0;r<8;r++) H0[(size_t)(r0+r)*HID + o0] = fmaxf(acc[0][r]+bb, 0.f);
  }
  if (h1v){
    float bb = b_in[o1];
    #pragma unroll
    for (int r=0;r<8;r++) H0[(size_t)(r0+r)*HID + o1] = fmaxf(acc[1][r]+bb, 0.f);
  }
}

// ---------------------------------------------------------------------------
// Fused 4-layer pipelined scan, d-SPLIT paired WGs + WAVE SPECIALIZATION:
// waves 8-15 (tid>=512) stream P(i+1) in 4 register-resident chunks placed in
// the B/C/D/E phase slots of step i (pre_s/xh/xf parity double-buffered);
// waves 0-7 run {R(i+1) || import+kd+softmax} -> B -> C -> D -> E.
// __launch_bounds__(1024, 4): LDS (136KB) caps us at 1 WG/CU = 4 waves/EU,
// where 128 VGPRs are free — without this the allocator targets 8 waves/EU,
// caps at 64 VGPRs and SPILLS the cross-barrier P accumulators to scratch
// (round-6 counters: 4.7GB FETCH / 4.4GB WRITE of spill traffic).
// ---------------------------------------------------------------------------
__global__ __launch_bounds__(1024, 4) void scan_pipe_kernel(
  float* __restrict__ Hball,
  const f16x2* __restrict__ W_M4, const f16x2* __restrict__ WrT4, const f16x2* __restrict__ W_P4,
  const float* __restrict__ bih_c, const float* __restrict__ bhh_c,
  const float* __restrict__ bih_p, const float* __restrict__ bhh_p,
  const float* __restrict__ gwq, const float* __restrict__ gwk, const float* __restrict__ gbv,
  const int* __restrict__ speakers, float* __restrict__ xrow, int* __restrict__ syncc,
  float* __restrict__ xhEx)
{
  (void)gwq; (void)gbv;   // softmax is shift-invariant: q and b cancel exactly
  __shared__ _Float16 Hh[2][NSEQ][304];
  __shared__ float pre_s[2][2][1800];   // [parity][chain][1800]
  __shared__ float gates[2][1800];
  __shared__ float Mf[2][304];
  __shared__ f16x2 Mh[2][152];
  __shared__ f16x2 u01h[2][304];
  __shared__ float wgt[2][NSEQ];
  __shared__ float kd[2][NSEQ];
  __shared__ float red[2][320];
  __shared__ float xf[2][2][304];       // [parity][chain][304]
  __shared__ f16x2 xh[2][2][152];       // [parity][chain][152]
  __shared__ int   spk[2][NSEQ];
  __shared__ int   startA[2][NSEQ];
  __shared__ int   sLayer, sPair, sHalf;

  const int tid = threadIdx.x;

  // --- claim (layer, pair, half) with XCD-local preference; 64 slots/layer ---
  if (tid == 0){
    int xcc = 0;
    asm volatile("s_getreg_b32 %0, hwreg(HW_REG_XCC_ID)" : "=s"(xcc));
    int pref = (xcc >> 1) & 3;
    int* claimc = syncc + 3*32*16 + 3*128*2*16;
    int l = 0, p = 0, hfv = 0;
    #pragma unroll 1
    for (int t=0; t<4; ++t){
      int cand = (pref + t) & 3;
      int idx = __hip_atomic_fetch_add(&claimc[cand*16], 1, __ATOMIC_RELAXED, __HIP_MEMORY_SCOPE_AGENT);
      if (idx < 64){ l = cand; p = idx>>1; hfv = idx&1; break; }
    }
    sLayer = l; sPair = p; sHalf = hfv;
  }
  __syncthreads();
  const int layer = sLayer;
  const int pair  = sPair;
  const int hf    = sHalf;
  const int base0 = (2*pair)*NSEQ;
  const int base1 = (2*pair+1)*NSEQ;

  const uint4* Wm4 = (const uint4*)(W_M4 + (size_t)layer*38*1800*4);
  const uint4* Wr4 = (const uint4*)(WrT4 + (size_t)layer*38*600*4);
  const uint4* Wp4 = (const uint4*)(W_P4 + (size_t)layer*38*1800*4);
  const float* HinB0 = Hball + (size_t)base0*300;
  const float* HinB1 = Hball + (size_t)base1*300;
  float* HoutB0 = Hball + ((size_t)(layer+1)*NROWS + (size_t)base0)*300;
  float* HoutB1 = Hball + ((size_t)(layer+1)*NROWS + (size_t)base1)*300;
  int* cntP = syncc + (layer*32 + pair)*16;
  int* cntC = (layer>0) ? (syncc + ((layer-1)*32 + pair)*16) : (int*)0;
  const float* xin  = xrow + (size_t)(((layer-1)*32 + pair)*2)*NSEQ*300;  // layer>0
  float*       xout = xrow + (size_t)((layer*32 + pair)*2)*NSEQ*300;      // layer<3

  // h-exchange pointers: per half, 2 parity slots x (2 chains x 150) f32
  const int lp = layer*32 + pair;
  float* xhMy = xhEx + ((size_t)lp*2 + hf)*600;
  const float* xhPt = xhEx + ((size_t)lp*2 + (1-hf))*600;
  int* fEmy = syncc + 1536 + (lp*2 + hf)*16;
  const int* fEpt = syncc + 1536 + (lp*2 + (1-hf))*16;

  const int w    = tid >> 6;   // wave id 0..15
  const int lane = tid & 63;

  // ---- E mapping: chain0 = tid 0..149, chain1 = tid 256..405 ----
  int ec = -1, ert = 0;
  if (tid < 150){ ec = 0; ert = tid; }
  else if (tid >= 256 && tid < 406){ ec = 1; ert = tid - 256; }
  float bcr=0,bcz=0,bcn=0,bpr=0,bpz=0,bpn=0,wkv=0; int deE=0;
  if (ec >= 0){
    deE = hf*150 + ert;
    bcr=bhh_c[layer*900+deE]; bcz=bhh_c[layer*900+300+deE]; bcn=bhh_c[layer*900+600+deE];
    bpr=bih_p[layer*900+deE]; bpz=bih_p[layer*900+300+deE]; bpn=bih_p[layer*900+600+deE];
    wkv=gwk[layer*300+deE];
  }
  // ---- import regs (waves 0,1): partner gwk, 3 per lane ----
  float wkp0=0, wkp1=0, wkp2=0;
  if (w < 2){
    const int pbase = layer*300 + (1-hf)*150;
    wkp0 = gwk[pbase + lane];
    wkp1 = gwk[pbase + 64 + lane];
    if (lane < 22) wkp2 = gwk[pbase + 128 + lane];
  }
  // ---- D rows (serial waves): r1 = tid, r2 = tid+512 ----
  int opmD1 = 0, opmD2 = 0; bool hasD2 = false;
  if (tid < 512){
    { int g = tid/150; opmD1 = g*300 + hf*150 + (tid - g*150); }
    hasD2 = (tid < 388);
    if (hasD2){ int r2 = tid+512; int g = r2/150; opmD2 = g*300 + hf*150 + (r2 - g*150); }
  }
  // ---- P rows (P waves): q1 = tid-512, q2 = tid ----
  int opmP1 = 0, opmP2 = 0; bool hasP2 = false; float ppbP1 = 0.f, ppbP2 = 0.f;
  if (tid >= 512){
    int q1 = tid - 512;
    { int g = q1/150; opmP1 = g*300 + hf*150 + (q1 - g*150); }
    ppbP1 = (opmP1<900) ? bih_c[layer*900+opmP1] : bhh_p[layer*900+(opmP1-900)];
    hasP2 = (tid < 900);
    if (hasP2){
      int q2 = tid; int g = q2/150; opmP2 = g*300 + hf*150 + (q2 - g*150);
      ppbP2 = (opmP2<900) ? bih_c[layer*900+opmP2] : bhh_p[layer*900+(opmP2-900)];
    }
  }
  const bool hasC2 = (tid < 88);   // C second row r2 = tid+512 < 600

  // ---- init LDS ----
  if (tid < 64) spk[0][tid] = speakers[base0+tid];
  else if (tid < 128) spk[1][tid-64] = speakers[base1+(tid-64)];
  for (int t=tid; t<2*1800; t+=1024) ((float*)gates)[t]=0.f;
  for (int t=tid; t<2*304; t+=1024) ((float*)Mf)[t]=0.f;
  if (tid >= 128 && tid < 168){ int t=tid-128; red[t/20][300+(t%20)] = 0.f; }
  if (tid >= 168 && tid < 176){
    int t=tid-168; f16x2 z; z.x=(_Float16)0.f; z.y=(_Float16)0.f;
    xh[t&1][(t>>1)&1][150+((t>>2)&1)] = z;   // both parities, both chains, both pad slots
  }
  if (tid >= 176 && tid < 180){
    int t=tid-176; f16x2 z; z.x=(_Float16)0.f; z.y=(_Float16)0.f;
    Mh[t>>1][150+(t&1)]=z;
    u01h[t>>1][150+(t&1)]=z; u01h[t>>1][302+(t&1)]=z;
  }
  __syncthreads();
  if (tid < 64){
    int s=0; for (int j=tid-1;j>=0;--j) if (spk[0][j]==spk[0][tid]){s=j;break;}
    startA[0][tid]=s;
  } else if (tid < 128){
    int t=tid-64;
    int s=0; for (int j=t-1;j>=0;--j) if (spk[1][j]==spk[1][t]){s=j;break;}
    startA[1][t]=s;
  }
  // producer must have finished steps 0 and 1 (R(0) + step0's R(1))
  if (layer>0 && tid==0){
    while (xloadi(cntC) < 4) __builtin_amdgcn_s_sleep(8);
  }
  __syncthreads();

  // ---- prologue R(0) -> parity 0 ----
  {
    int rcR=-1, rtR=0;
    if (tid>=128 && tid<278){ rcR=0; rtR=tid-128; }
    else if (tid>=288 && tid<438){ rcR=1; rtR=tid-288; }
    if (rcR >= 0){
      float x0, x1;
      if (layer==0){
        const float* Hin = rcR ? HinB1 : HinB0;
        float2 v = *(const float2*)(Hin + 2*rtR);
        x0=v.x; x1=v.y;
      } else {
        const float* xi = xin + (size_t)rcR*NSEQ*300;
        x0 = xload(xi + 2*rtR);
        x1 = xload(xi + 2*rtR + 1);
      }
      xf[0][rcR][2*rtR]=x0; xf[0][rcR][2*rtR+1]=x1;
      f16x2 h; h.x=(_Float16)x0; h.y=(_Float16)x1; xh[0][rcR][rtR]=h;
    }
  }
  __syncthreads();
  // ---- prologue P(0) -> pre_s[0] ----
  if (tid >= 512){
    const int np = 0;
    float p1a0=0,p1a1=0,p1a2=0,p1a3=0,p1b0=0,p1b1=0,p1b2=0,p1b3=0;
    float p2a0=0,p2a1=0,p2a2=0,p2a3=0,p2b0=0,p2b1=0,p2b2=0,p2b3=0;
    PCH(0,38)
    pre_s[np][0][opmP1] = (p1a0+p1a1)+(p1a2+p1a3) + ppbP1;
    pre_s[np][1][opmP1] = (p1b0+p1b1)+(p1b2+p1b3) + ppbP1;
    if (hasP2){
      pre_s[np][0][opmP2] = (p2a0+p2a1)+(p2a2+p2a3) + ppbP2;
      pre_s[np][1][opmP2] = (p2b0+p2b1)+(p2b2+p2b3) + ppbP2;
    }
  }
  __syncthreads();

  for (int i=0; i<NSEQ; ++i){
    const int cur = i&1, np = cur^1;
    // P(i+1) chunk accumulators (live across the step's phase slots)
    float p1a0=0,p1a1=0,p1a2=0,p1a3=0,p1b0=0,p1b1=0,p1b2=0,p1b3=0;
    float p2a0=0,p2a1=0,p2a2=0,p2a3=0,p2b0=0,p2b1=0,p2b2=0,p2b3=0;

    // ---- ph1: R(i+1) on tid 128-437  ||  import+kd+softmax on waves 0,1 ----
    if (i < 63){
      int rcR=-1, rtR=0;
      if (tid>=128 && tid<278){ rcR=0; rtR=tid-128; }
      else if (tid>=288 && tid<438){ rcR=1; rtR=tid-288; }
      if (rcR >= 0){
        float x0, x1;
        if (layer==0){
          const float* Hin = rcR ? HinB1 : HinB0;
          float2 v = *(const float2*)(Hin + (size_t)(i+1)*300 + 2*rtR);
          x0=v.x; x1=v.y;
        } else {
          const float* xi = xin + (size_t)rcR*NSEQ*300 + (size_t)(i+1)*300;
          x0 = xload(xi + 2*rtR);
          x1 = xload(xi + 2*rtR + 1);
        }
        xf[np][rcR][2*rtR]=x0; xf[np][rcR][2*rtR+1]=x1;
        f16x2 h; h.x=(_Float16)x0; h.y=(_Float16)x1; xh[np][rcR][rtR]=h;
      }
    }
    if (w < 2 && i > 0){
      const int c = w;
      while (xloadi(fEpt) < i) __builtin_amdgcn_s_sleep(1);
      const int par = ((i-1)&1)*300 + c*150;
      const int pb = (1-hf)*150;
      float hv0 = xload(xhPt + par + lane);
      float hv1 = xload(xhPt + par + 64 + lane);
      float hv2 = (lane<22) ? xload(xhPt + par + 128 + lane) : 0.f;
      red[c][pb+lane] = hv0*wkp0;      Hh[c][i-1][pb+lane] = (_Float16)hv0;
      red[c][pb+64+lane] = hv1*wkp1;   Hh[c][i-1][pb+64+lane] = (_Float16)hv1;
      if (lane<22){ red[c][pb+128+lane] = hv2*wkp2; Hh[c][i-1][pb+128+lane] = (_Float16)hv2; }
      float s = red[c][lane]+red[c][lane+64]+red[c][lane+128]+red[c][lane+192]+red[c][lane+256];
      #pragma unroll
      for (int o=32;o>0;o>>=1) s += __shfl_xor(s,o);
      if (lane==0) kd[c][i-1]=s;
      {
        const int st = startA[c][i];
        const bool in = (lane>=st) && (lane<i);
        float kv = (lane==i-1) ? s : kd[c][lane];
        float a = in ? kv : -3.0e38f;
        float m = a;
        #pragma unroll
        for (int o=32;o>0;o>>=1) m = fmaxf(m,__shfl_xor(m,o));
        float e = in ? __expf(a-m) : 0.f;
        float ss = e;
        #pragma unroll
        for (int o=32;o>0;o>>=1) ss += __shfl_xor(ss,o);
        wgt[c][lane] = e/ss;
      }
    }
    __syncthreads();                                        // bar1

    // ---- ph2: B (serial)  ||  P chunk 0 ----
    if (tid < 512){
      if (i > 0){
        #pragma unroll 1
        for (int pass=0; pass<3; ++pass){
          int T = tid + pass*512;
          if (T < 1200){
            const int c = (T >= 600);
            const int t = T - c*600;
            const int d  = (t<300)? t : (t-300);
            const int wh = (t>=300);
            const int st = startA[c][i]; const int ms = spk[c][i];
            float u=0.f;
            for (int j=st;j<i;++j){
              float sel = ((spk[c][j]==ms) != (wh!=0)) ? 1.f : 0.f;
              u += sel*wgt[c][j]*(float)Hh[c][j][d];
            }
            ((_Float16*)&u01h[c][0])[(wh?304:0) + d] = (_Float16)u;
          }
        }
      }
    } else if (i < 63){
      PCH(0,10)
    }
    __syncthreads();                                        // bar2

    // ---- ph3: C (serial, dual-row)  ||  P chunk 1 ----
    if (tid < 512){
      if (i > 0){
        const int hh = tid&1;
        const f16x2* uA = (const f16x2*)&u01h[0][0] + hh*152;
        const f16x2* uB = (const f16x2*)&u01h[1][0] + hh*152;
        float a0=0,a1=0,a2=0,a3=0, b0=0,b1=0,b2=0,b3=0;
        float e0=0,e1=0,e2=0,e3=0, f0=0,f1=0,f2=0,f3=0;
        for (int kg=0;kg<38;kg++){
          U v1; v1.u = Wr4[(size_t)kg*600 + tid];
          U v2; if (hasC2) v2.u = Wr4[(size_t)kg*600 + tid + 512];
          f16x2 uA0=uA[kg*4+0],uA1=uA[kg*4+1],uA2=uA[kg*4+2],uA3=uA[kg*4+3];
          f16x2 uB0=uB[kg*4+0],uB1=uB[kg*4+1],uB2=uB[kg*4+2],uB3=uB[kg*4+3];
          a0=fdot2a(v1.h[0],uA0,a0); a1=fdot2a(v1.h[1],uA1,a1);
          a2=fdot2a(v1.h[2],uA2,a2); a3=fdot2a(v1.h[3],uA3,a3);
          b0=fdot2a(v1.h[0],uB0,b0); b1=fdot2a(v1.h[1],uB1,b1);
          b2=fdot2a(v1.h[2],uB2,b2); b3=fdot2a(v1.h[3],uB3,b3);
          if (hasC2){
            e0=fdot2a(v2.h[0],uA0,e0); e1=fdot2a(v2.h[1],uA1,e1);
            e2=fdot2a(v2.h[2],uA2,e2); e3=fdot2a(v2.h[3],uA3,e3);
            f0=fdot2a(v2.h[0],uB0,f0); f1=fdot2a(v2.h[1],uB1,f1);
            f2=fdot2a(v2.h[2],uB2,f2); f3=fdot2a(v2.h[3],uB3,f3);
          }
        }
        float aA = (a0+a1)+(a2+a3);
        float aB = (b0+b1)+(b2+b3);
        float m2A = aA + __shfl_xor(aA,1);
        float m2B = aB + __shfl_xor(aB,1);
        if ((tid&1)==0){ Mf[0][tid>>1] = m2A; Mf[1][tid>>1] = m2B; }
        float moA = __shfl_xor(m2A,2);
        float moB = __shfl_xor(m2B,2);
        if ((tid&3)==0){
          f16x2 hA; hA.x=(_Float16)m2A; hA.y=(_Float16)moA; Mh[0][tid>>2]=hA;
          f16x2 hB; hB.x=(_Float16)m2B; hB.y=(_Float16)moB; Mh[1][tid>>2]=hB;
        }
        if (hasC2){
          const int r2 = tid + 512;
          float cA = (e0+e1)+(e2+e3);
          float cB = (f0+f1)+(f2+f3);
          float n2A = cA + __shfl_xor(cA,1);
          float n2B = cB + __shfl_xor(cB,1);
          if ((tid&1)==0){ Mf[0][r2>>1] = n2A; Mf[1][r2>>1] = n2B; }
          float noA = __shfl_xor(n2A,2);
          float noB = __shfl_xor(n2B,2);
          if ((tid&3)==0){
            f16x2 hA; hA.x=(_Float16)n2A; hA.y=(_Float16)noA; Mh[0][r2>>2]=hA;
            f16x2 hB; hB.x=(_Float16)n2B; hB.y=(_Float16)noB; Mh[1][r2>>2]=hB;
          }
        }
      }
    } else if (i < 63){
      PCH(10,20)
    }
    __syncthreads();                                        // bar3

    // ---- ph4: D (serial, dual-row)  ||  P chunk 2 ----
    if (tid < 512){
      if (i > 0){
        float a0=0,a1=0,a2=0,a3=0, b0=0,b1=0,b2=0,b3=0;
        float e0=0,e1=0,e2=0,e3=0, f0=0,f1=0,f2=0,f3=0;
        for (int kg=0;kg<38;kg++){
          U v1; v1.u = Wm4[(size_t)kg*1800 + opmD1];
          U v2; if (hasD2) v2.u = Wm4[(size_t)kg*1800 + opmD2];
          f16x2 mA0=Mh[0][kg*4+0], mA1=Mh[0][kg*4+1], mA2=Mh[0][kg*4+2], mA3=Mh[0][kg*4+3];
          f16x2 mB0=Mh[1][kg*4+0], mB1=Mh[1][kg*4+1], mB2=Mh[1][kg*4+2], mB3=Mh[1][kg*4+3];
          a0=fdot2a(v1.h[0],mA0,a0); a1=fdot2a(v1.h[1],mA1,a1);
          a2=fdot2a(v1.h[2],mA2,a2); a3=fdot2a(v1.h[3],mA3,a3);
          b0=fdot2a(v1.h[0],mB0,b0); b1=fdot2a(v1.h[1],mB1,b1);
          b2=fdot2a(v1.h[2],mB2,b2); b3=fdot2a(v1.h[3],mB3,b3);
          if (hasD2){
            e0=fdot2a(v2.h[0],mA0,e0); e1=fdot2a(v2.h[1],mA1,e1);
            e2=fdot2a(v2.h[2],mA2,e2); e3=fdot2a(v2.h[3],mA3,e3);
            f0=fdot2a(v2.h[0],mB0,f0); f1=fdot2a(v2.h[1],mB1,f1);
            f2=fdot2a(v2.h[2],mB2,f2); f3=fdot2a(v2.h[3],mB3,f3);
          }
        }
        gates[0][opmD1] = (a0+a1)+(a2+a3);
        gates[1][opmD1] = (b0+b1)+(b2+b3);
        if (hasD2){
          gates[0][opmD2] = (e0+e1)+(e2+e3);
          gates[1][opmD2] = (f0+f1)+(f2+f3);
        }
      }
    } else if (i < 63){
      PCH(20,29)
    }
    __syncthreads();                                        // bar4

    // ---- ph5: E (serial)  ||  P chunk 3 + pre_s[np] write ----
    if (ec >= 0){
      const int de = deE;
      const float M = Mf[ec][de];
      const float* ps = pre_s[cur][ec];
      const float* gs = gates[ec];
      float r  = sigm(ps[de] + gs[de] + bcr);
      float z  = sigm(ps[300+de] + gs[300+de] + bcz);
      float n  = tanhf(ps[600+de] + r*(gs[600+de]+bcn));
      float C  = (1.f-z)*n + z*M;
      float rp = sigm(gs[900+de]+bpr + ps[900+de]);
      float zp = sigm(gs[1200+de]+bpz + ps[1200+de]);
      float np_ = tanhf(gs[1500+de]+bpn + rp*ps[1500+de]);
      float qv = xf[cur][ec][de];
      float P  = (1.f-zp)*np_ + zp*qv;
      float h  = C + P;
      Hh[ec][i][de] = (_Float16)h;
      red[ec][de] = h*wkv;
      float* Ho = ec ? HoutB1 : HoutB0;
      Ho[(size_t)i*300 + de] = h;
      xstore(xhMy + (i&1)*300 + ec*150 + ert, h);
      if (layer<3) xstore(xout + (size_t)ec*NSEQ*300 + (size_t)i*300 + de, h);
    }
    if (tid >= 512 && i < 63){
      PCH(29,38)
      pre_s[np][0][opmP1] = (p1a0+p1a1)+(p1a2+p1a3) + ppbP1;
      pre_s[np][1][opmP1] = (p1b0+p1b1)+(p1b2+p1b3) + ppbP1;
      if (hasP2){
        pre_s[np][0][opmP2] = (p2a0+p2a1)+(p2a2+p2a3) + ppbP2;
        pre_s[np][1][opmP2] = (p2b0+p2b1)+(p2b2+p2b3) + ppbP2;
      }
    }
    asm volatile("s_waitcnt vmcnt(0)" ::: "memory");   // drain publish before flags
    __syncthreads();                                        // bar5
    if (tid==0){
      __hip_atomic_fetch_add(fEmy, 1, __ATOMIC_RELAXED, __HIP_MEMORY_SCOPE_AGENT);
      if (layer<3) __hip_atomic_fetch_add(cntP, 1, __ATOMIC_RELAXED, __HIP_MEMORY_SCOPE_AGENT);
      if (layer>0 && i<62){
        while (xloadi(cntC) < 2*(i+3)) __builtin_amdgcn_s_sleep(8);
      }
    }
    __syncthreads();                                        // bar6
  }
}

// ---------------------------------------------------------------------------
// Head with fp16-dot2 GEMMs (unchanged).
// ---------------------------------------------------------------------------
__global__ __launch_bounds__(256) void head_kernel(
  const float* __restrict__ H0, const float* __restrict__ Hl1,
  const float* __restrict__ Hl2, const float* __restrict__ Hl3,
  const float* __restrict__ Hl4, const float* __restrict__ feat,
  const f16x2* __restrict__ W14, const float* __restrict__ b1,
  const f16x2* __restrict__ W24, const float* __restrict__ b2,
  const float* __restrict__ w3, const float* __restrict__ b3,
  float* __restrict__ out)
{
  const int tid = threadIdx.x;
  const int r0  = blockIdx.x*16;
  __shared__ f16x2 Xh[16*256];
  __shared__ _Float16 h1h[16*304];
  __shared__ float S2[16*304];
  const uint4* W14u = (const uint4*)W14;
  const uint4* W24u = (const uint4*)W24;

  float acc0[16], acc1[16];
  #pragma unroll
  for (int r=0;r<16;r++){ acc0[r]=0.f; acc1[r]=0.f; }
  const int o  = tid;
  const int o2 = tid + 256;
  const bool has2 = (o2 < 300);

  #pragma unroll
  for (int seg=0; seg<7; seg++){
    const float* src = (seg==0)?H0:(seg==1)?Hl1:(seg==2)?Hl2:(seg==3)?Hl3:(seg==4)?Hl4:feat;
    if (seg < 5){
      for (int t=tid; t<16*152; t+=256){
        int r=t/152, p=t-r*152, c=2*p;
        float v0 = (c<300)? src[(size_t)(r0+r)*300 + c] : 0.f;
        float v1 = (c+1<300)? src[(size_t)(r0+r)*300 + c+1] : 0.f;
        f16x2 h; h.x=(_Float16)v0; h.y=(_Float16)v1;
        Xh[r*256+p] = h;
      }
    } else {
      const int cb = (seg-5)*512;
      for (int t=tid; t<16*256; t+=256){
        int r=t>>8, p=t&255;
        float v0 = src[(size_t)(r0+r)*1024 + cb + 2*p];
        float v1 = src[(size_t)(r0+r)*1024 + cb + 2*p+1];
        f16x2 h; h.x=(_Float16)v0; h.y=(_Float16)v1;
        Xh[r*256+p] = h;
      }
    }
    __syncthreads();
    const int kgs = (seg<5)?38:64;
    const int kgo = (seg<5)? seg*38 : 190+(seg-5)*64;
    if (o < 300){
      for (int kg=0; kg<kgs; kg++){
        U a, b;
        a.u = W14u[(size_t)(kgo+kg)*304 + o];
        if (has2) b.u = W14u[(size_t)(kgo+kg)*304 + o2];
        #pragma unroll
        for (int r=0;r<16;r++){
          const f16x2* xp = &Xh[r*256 + kg*4];
          float t0 = fdot2a(a.h[0], xp[0], 0.f);
          t0 = fdot2a(a.h[1], xp[1], t0);
          t0 = fdot2a(a.h[2], xp[2], t0);
          t0 = fdot2a(a.h[3], xp[3], t0);
          acc0[r] += t0;
          if (has2){
            float t1 = fdot2a(b.h[0], xp[0], 0.f);
            t1 = fdot2a(b.h[1], xp[1], t1);
            t1 = fdot2a(b.h[2], xp[2], t1);
            t1 = fdot2a(b.h[3], xp[3], t1);
            acc1[r] += t1;
          }
        }
      }
    }
    __syncthreads();
  }
  if (o < 300){
    float bb = b1[o];
    #pragma unroll
    for (int r=0;r<16;r++) h1h[r*304+o] = (_Float16)fmaxf(acc0[r]+bb, 0.f);
  }
  if (has2){
    float bb = b1[o2];
    #pragma unroll
    for (int r=0;r<16;r++) h1h[r*304+o2] = (_Float16)fmaxf(acc1[r]+bb, 0.f);
  }
  if (tid < 4){
    #pragma unroll
    for (int r=0;r<16;r++) h1h[r*304+300+tid] = (_Float16)0.f;
  }
  __syncthreads();
  #pragma unroll
  for (int r=0;r<16;r++){ acc0[r]=0.f; acc1[r]=0.f; }
  if (o < 300){
    for (int kg=0; kg<38; kg++){
      U a, b;
      a.u = W24u[(size_t)kg*304 + o];
      if (has2) b.u = W24u[(size_t)kg*304 + o2];
      #pragma unroll
      for (int r=0;r<16;r++){
        const f16x2* xp = (const f16x2*)&h1h[r*304] + kg*4;
        float t0 = fdot2a(a.h[0], xp[0], 0.f);
        t0 = fdot2a(a.h[1], xp[1], t0);
        t0 = fdot2a(a.h[2], xp[2], t0);
        t0 = fdot2a(a.h[3], xp[3], t0);
        acc0[r] += t0;
        if (has2){
          float t1 = fdot2a(b.h[0], xp[0], 0.f);
          t1 = fdot2a(b.h[1], xp[1], t1);
          t1 = fdot2a(b.h[2], xp[2], t1);
          t1 = fdot2a(b.h[3], xp[3], t1);
          acc1[r] += t1;
        }
      }
    }
  }
  __syncthreads();
  if (o < 300){
    float bb = b2[o];
    #pragma unroll
    for (int r=0;r<16;r++) S2[r*304+o] = fmaxf(acc0[r]+bb, 0.f);
  }
  if (has2){
    float bb = b2[o2];
    #pragma unroll
    for (int r=0;r<16;r++) S2[r*304+o2] = fmaxf(acc1[r]+bb, 0.f);
  }
  __syncthreads();
  if (tid < 16*7){
    int r = tid/7, c = tid - r*7;
    float s = b3[c];
    const float* wrow = w3 + (size_t)c*HID;
    for (int k=0;k<300;k++) s += wrow[k]*S2[r*304+k];
    out[(size_t)(r0+r)*7 + c] = s;
  }
}

// ---------------------------------------------------------------------------
extern "C" void kernel_launch(void* const* d_in, const int* in_sizes, int n_in,
                              void* d_out, int out_size, void* d_ws, size_t ws_size,
                              hipStream_t stream)
{
  (void)in_sizes; (void)n_in; (void)out_size; (void)ws_size;
  const float* feat  = (const float*)d_in[0];
  const int*   spk   = (const int*)d_in[1];
  const float* w_in  = (const float*)d_in[2];
  const float* b_in  = (const float*)d_in[3];
  const float* gwq   = (const float*)d_in[4];
  const float* gwk   = (const float*)d_in[5];
  const float* gb    = (const float*)d_in[6];
  const float* wr0   = (const float*)d_in[7];
  const float* wr1   = (const float*)d_in[8];
  const float* wih_c = (const float*)d_in[9];
  const float* whh_c = (const float*)d_in[10];
  const float* bih_c = (const float*)d_in[11];
  const float* bhh_c = (const float*)d_in[12];
  const float* wih_p = (const float*)d_in[13];
  const float* whh_p = (const float*)d_in[14];
  const float* bih_p = (const float*)d_in[15];
  const float* bhh_p = (const float*)d_in[16];
  const float* w1    = (const float*)d_in[17];
  const float* b1    = (const float*)d_in[18];
  const float* w2    = (const float*)d_in[19];
  const float* b2    = (const float*)d_in[20];
  const float* w3    = (const float*)d_in[21];
  const float* b3    = (const float*)d_in[22];
  float* out = (float*)d_out;

  char* ws = (char*)d_ws;
  size_t off = 0;
  auto alloc = [&](size_t bytes)->void*{
    void* p = ws + off;
    off += (bytes + 255) & ~(size_t)255;
    return p;
  };
  f16x2* W_M4 = (f16x2*)alloc((size_t)4*38*1800*4 * sizeof(f16x2));
  f16x2* WrT4 = (f16x2*)alloc((size_t)4*38*600*4  * sizeof(f16x2));
  f16x2* W_P4 = (f16x2*)alloc((size_t)4*38*1800*4 * sizeof(f16x2));
  f16x2* W_H4 = (f16x2*)alloc((size_t)128*300*4   * sizeof(f16x2));
  f16x2* W_14 = (f16x2*)alloc((size_t)318*304*4   * sizeof(f16x2));
  f16x2* W_24 = (f16x2*)alloc((size_t)38*304*4    * sizeof(f16x2));
  float* Hball = (float*)alloc((size_t)5*NROWS*HID*sizeof(float));
  float* xrow  = (float*)alloc((size_t)3*64*NSEQ*HID*sizeof(float));
  int*   syncc = (int*)alloc((size_t)NSYNC*sizeof(int));
  float* xhEx  = (float*)alloc((size_t)128*2*600*sizeof(float));

  {
    const int tot = 4*38*1800*4 + 4*38*600*4 + 4*38*1800*4 + 128*300*4
                  + 318*304*4 + 38*304*4 + NSYNC;
    convert_all_kernel<<<(tot+255)/256, 256, 0, stream>>>(whh_c, wih_p, wih_c, whh_p,
        wr0, wr1, w_in, w1, w2, W_M4, WrT4, W_P4, W_H4, W_14, W_24, syncc);
  }
  h0_kernel<<<NROWS/8, 256, 0, stream>>>(feat, W_H4, b_in, Hball);

  scan_pipe_kernel<<<256, 1024, 0, stream>>>(Hball, W_M4, WrT4, W_P4,
      bih_c, bhh_c, bih_p, bhh_p, gwq, gwk, gb, spk, xrow, syncc, xhEx);

  head_kernel<<<NROWS/16, 256, 0, stream>>>(
      Hball, Hball + (size_t)NROWS*HID, Hball + (size_t)2*NROWS*HID,
      Hball + (size_t)3*NROWS*HID, Hball + (size_t)4*NROWS*HID,
      feat, W_14, b1, W_24, b2, w3, b3, out);
}

// Round 9
// 2201.901 us; speedup vs baseline: 3.6030x; 3.5829x over previous
//
#include <hip/hip_runtime.h>
#include <hip/hip_bf16.h>

typedef _Float16 f16x2 __attribute__((ext_vector_type(2)));

#define HID 300
#define NSEQ 64
#define NROWS 4096   // B*N = 64*64

union U { uint4 u; f16x2 h[4]; };

__device__ __forceinline__ float sigm(float x){ return 1.f/(1.f+__expf(-x)); }

__device__ __forceinline__ float fdot2a(f16x2 a, f16x2 b, float c){
#if __has_builtin(__builtin_amdgcn_fdot2)
  return __builtin_amdgcn_fdot2(a, b, c, false);
#else
  return c + (float)a.x*(float)b.x + (float)a.y*(float)b.y;
#endif
}

// Relaxed agent-scope ops: LLC-coherent, NO cache maintenance (no L2 flush).
__device__ __forceinline__ void xstore(float* p, float v){
  __hip_atomic_store(p, v, __ATOMIC_RELAXED, __HIP_MEMORY_SCOPE_AGENT);
}
__device__ __forceinline__ float xload(const float* p){
  return __hip_atomic_load(p, __ATOMIC_RELAXED, __HIP_MEMORY_SCOPE_AGENT);
}
__device__ __forceinline__ int xloadi(const int* p){
  return __hip_atomic_load(p, __ATOMIC_RELAXED, __HIP_MEMORY_SCOPE_AGENT);
}

// sync area layout (ints):
//   [0, 1536)            : cross-layer step counters (3 layers x 32 pairs x 16)
//   [1536, 1536+4096)    : fE flags (h-exchange, 128 pairs x 2 halves x 16)
//   [13824, 13824+64)    : claim pools (4 layers x 16)   (gap kept zeroed)
#define NSYNC (3*32*16 + 3*128*2*16 + 64)

// P-group: ONE row's complete 38-kg dot against xh[np], written immediately.
// Accumulators live only within the enclosing phase -> no cross-barrier
// register pressure (the R6/R8 spill source).
#define PGRP(OPMv, PPBv) do { \
    float a0=0,a1=0,a2=0,a3=0, b0=0,b1=0,b2=0,b3=0; \
    for (int kg=0; kg<38; ++kg){ \
      U v; v.u = Wp4[(size_t)kg*1800 + (OPMv)]; \
      f16x2 xA0=xh[np][0][kg*4+0],xA1=xh[np][0][kg*4+1],xA2=xh[np][0][kg*4+2],xA3=xh[np][0][kg*4+3]; \
      f16x2 xB0=xh[np][1][kg*4+0],xB1=xh[np][1][kg*4+1],xB2=xh[np][1][kg*4+2],xB3=xh[np][1][kg*4+3]; \
      a0=fdot2a(v.h[0],xA0,a0); a1=fdot2a(v.h[1],xA1,a1); \
      a2=fdot2a(v.h[2],xA2,a2); a3=fdot2a(v.h[3],xA3,a3); \
      b0=fdot2a(v.h[0],xB0,b0); b1=fdot2a(v.h[1],xB1,b1); \
      b2=fdot2a(v.h[2],xB2,b2); b3=fdot2a(v.h[3],xB3,b3); \
    } \
    pre_s[np][0][(OPMv)] = (a0+a1)+(a2+a3) + (PPBv); \
    pre_s[np][1][(OPMv)] = (b0+b1)+(b2+b3) + (PPBv); \
  } while(0)

// ---------------------------------------------------------------------------
// Merged repack: f32 -> fp16 pairs, [kg][outs][4 pairs] coalesced; also zeroes
// the pipeline sync counters + claim pools every launch.
// ---------------------------------------------------------------------------
__global__ void convert_all_kernel(
    const float* __restrict__ whh_c, const float* __restrict__ wih_p,
    const float* __restrict__ wih_c, const float* __restrict__ whh_p,
    const float* __restrict__ wr0,   const float* __restrict__ wr1,
    const float* __restrict__ w_in,  const float* __restrict__ w1,
    const float* __restrict__ w2,
    f16x2* __restrict__ W_M4, f16x2* __restrict__ WrT4, f16x2* __restrict__ W_P4,
    f16x2* __restrict__ W_H4, f16x2* __restrict__ W_14, f16x2* __restrict__ W_24,
    int* __restrict__ syncc)
{
  const int NA = 4*38*1800*4;
  const int NB = 4*38*600*4;
  const int NP = 4*38*1800*4;
  const int NH = 128*300*4;
  const int N1 = 318*304*4;
  const int N2 = 38*304*4;
  const int NS = NSYNC;
  const int TOT = NA+NB+NP+NH+N1+N2+NS;
  for (int idx0 = blockIdx.x*blockDim.x + threadIdx.x; idx0 < TOT; idx0 += gridDim.x*blockDim.x){
    int idx = idx0;
    if (idx < NA){
      int l    = idx/(38*1800*4);
      int rem  = idx - l*(38*1800*4);
      int kg   = rem/(1800*4);
      int rem2 = rem - kg*(1800*4);
      int o = rem2>>2, s = rem2&3;
      int c = (kg*4+s)*2;
      float v0=0.f, v1=0.f;
      if (c < 300){
        const float* src = (o<900) ? (whh_c + ((size_t)l*900+o)*300)
                                   : (wih_p + ((size_t)l*900+(o-900))*300);
        v0 = src[c]; v1 = src[c+1];
      }
      f16x2 t; t.x=(_Float16)v0; t.y=(_Float16)v1;
      W_M4[idx] = t; continue;
    }
    idx -= NA;
    if (idx < NB){
      int l    = idx/(38*600*4);
      int rem  = idx - l*(38*600*4);
      int kg   = rem/(600*4);
      int rem2 = rem - kg*(600*4);
      int t6 = rem2>>2, s = rem2&3;
      int d = t6>>1, hh = t6&1;
      int c = (kg*4+s)*2;
      float v0=0.f, v1=0.f;
      if (c < 300){
        const float* src = hh ? (wr1 + ((size_t)l*300+d)*300)
                              : (wr0 + ((size_t)l*300+d)*300);
        v0 = src[c]; v1 = src[c+1];
      }
      f16x2 t; t.x=(_Float16)v0; t.y=(_Float16)v1;
      WrT4[idx] = t; continue;
    }
    idx -= NB;
    if (idx < NP){
      int l    = idx/(38*1800*4);
      int rem  = idx - l*(38*1800*4);
      int kg   = rem/(1800*4);
      int rem2 = rem - kg*(1800*4);
      int o = rem2>>2, s = rem2&3;
      int c = (kg*4+s)*2;
      float v0=0.f, v1=0.f;
      if (c < 300){
        const float* src = (o<900) ? (wih_c + ((size_t)l*900+o)*300)
                                   : (whh_p + ((size_t)l*900+(o-900))*300);
        v0 = src[c]; v1 = src[c+1];
      }
      f16x2 t; t.x=(_Float16)v0; t.y=(_Float16)v1;
      W_P4[idx] = t; continue;
    }
    idx -= NP;
    if (idx < NH){
      int kg  = idx/(300*4);
      int rem = idx - kg*(300*4);
      int o = rem>>2, s = rem&3;
      int c = (kg*4+s)*2;
      f16x2 t; t.x=(_Float16)w_in[(size_t)o*1024+c]; t.y=(_Float16)w_in[(size_t)o*1024+c+1];
      W_H4[idx] = t; continue;
    }
    idx -= NH;
    if (idx < N1){
      int kgg = idx/(304*4);
      int rem = idx - kgg*(304*4);
      int o = rem>>2, s = rem&3;
      int segbase, seglen, kgl;
      if (kgg < 190){ int seg = kgg/38; kgl = kgg - seg*38; segbase = seg*300; seglen = 300; }
      else { int kk = kgg-190; int sf = kk>>6; kgl = kk&63; segbase = 1500 + sf*512; seglen = 512; }
      int c = (kgl*4+s)*2;
      float v0=0.f, v1=0.f;
      if (o < 300 && c < seglen){
        v0 = w1[(size_t)o*2524 + segbase + c];
        if (c+1 < seglen) v1 = w1[(size_t)o*2524 + segbase + c + 1];
      }
      f16x2 t; t.x=(_Float16)v0; t.y=(_Float16)v1;
      W_14[idx] = t; continue;
    }
    idx -= N1;
    if (idx < N2){
      int kg = idx/(304*4);
      int rem = idx - kg*(304*4);
      int o = rem>>2, s = rem&3;
      int c = (kg*4+s)*2;
      float v0=0.f, v1=0.f;
      if (o < 300 && c < 300){ v0 = w2[(size_t)o*300+c]; v1 = w2[(size_t)o*300+c+1]; }
      f16x2 t; t.x=(_Float16)v0; t.y=(_Float16)v1;
      W_24[idx] = t; continue;
    }
    idx -= N2;
    syncc[idx] = 0;
  }
}

// ---------------------------------------------------------------------------
// H0 = relu(features @ w_in^T + b_in), coalesced fp16 weights.
// ---------------------------------------------------------------------------
__global__ __launch_bounds__(256) void h0_kernel(const float* __restrict__ feat,
    const f16x2* __restrict__ WH, const float* __restrict__ b_in, float* __restrict__ H0)
{
  const int tid = threadIdx.x;
  const int r0  = blockIdx.x*8;
  __shared__ f16x2 X[8][512];
  for (int t=tid; t<8*512; t+=256){
    int r=t>>9, p=t&511, c=2*p;
    f16x2 h; h.x=(_Float16)feat[(size_t)(r0+r)*1024+c];
    h.y=(_Float16)feat[(size_t)(r0+r)*1024+c+1];
    X[r][p]=h;
  }
  __syncthreads();
  const uint4* WHu = (const uint4*)WH;
  const int o0 = tid, o1 = tid+256;
  const bool h1v = (o1 < 300);
  float acc[2][8];
  #pragma unroll
  for (int j=0;j<2;j++)
    #pragma unroll
    for (int r=0;r<8;r++) acc[j][r]=0.f;
  for (int kg=0; kg<128; kg++){
    U w0, w1;
    w0.u = WHu[(size_t)kg*300 + o0];
    if (h1v) w1.u = WHu[(size_t)kg*300 + o1];
    #pragma unroll
    for (int r=0;r<8;r++){
      const f16x2* xp = &X[r][kg*4];
      f16x2 x0=xp[0],x1=xp[1],x2=xp[2],x3=xp[3];
      acc[0][r] = fdot2a(w0.h[3],x3, fdot2a(w0.h[2],x2, fdot2a(w0.h[1],x1, fdot2a(w0.h[0],x0, acc[0][r]))));
      if (h1v)
        acc[1][r] = fdot2a(w1.h[3],x3, fdot2a(w1.h[2],x2, fdot2a(w1.h[1],x1, fdot2a(w1.h[0],x0, acc[1][r]))));
    }
  }
  {
    float bb = b_in[o0];
    #pragma unroll
    for (int r=0;r<8;r++) H0[(size_t)(r0+r)*HID + o0] = fmaxf(acc[0][r]+bb, 0.f);
  }
  if (h1v){
    float bb = b_in[o1];
    #pragma unroll
    for (int r=0;r<8;r++) H0[(size_t)(r0+r)*HID + o1] = fmaxf(acc[1][r]+bb, 0.f);
  }
}

// ---------------------------------------------------------------------------
// Fused 4-layer pipelined scan, d-SPLIT paired WGs + WAVE SPECIALIZATION:
// waves 8-15 (tid>=512): P(i+1) split into 3 ROW-GROUPS of 300; each group
// runs its FULL 38-kg dot inside one phase slot (ph2/ph3/ph4) and writes
// pre_s immediately — accumulators never live across a barrier (the R6/R8
// scratch-spill source). Waves 0-7: {R(i+1) || import+kd+softmax} -> B -> C
// -> D -> E. pre_s/xh/xf parity double-buffered; producer lead = 2 steps.
// ---------------------------------------------------------------------------
__global__ __launch_bounds__(1024) void scan_pipe_kernel(
  float* __restrict__ Hball,
  const f16x2* __restrict__ W_M4, const f16x2* __restrict__ WrT4, const f16x2* __restrict__ W_P4,
  const float* __restrict__ bih_c, const float* __restrict__ bhh_c,
  const float* __restrict__ bih_p, const float* __restrict__ bhh_p,
  const float* __restrict__ gwq, const float* __restrict__ gwk, const float* __restrict__ gbv,
  const int* __restrict__ speakers, float* __restrict__ xrow, int* __restrict__ syncc,
  float* __restrict__ xhEx)
{
  (void)gwq; (void)gbv;   // softmax is shift-invariant: q and b cancel exactly
  __shared__ _Float16 Hh[2][NSEQ][304];
  __shared__ float pre_s[2][2][1800];   // [parity][chain][1800]
  __shared__ float gates[2][1800];
  __shared__ float Mf[2][304];
  __shared__ f16x2 Mh[2][152];
  __shared__ f16x2 u01h[2][304];
  __shared__ float wgt[2][NSEQ];
  __shared__ float kd[2][NSEQ];
  __shared__ float red[2][320];
  __shared__ float xf[2][2][304];       // [parity][chain][304]
  __shared__ f16x2 xh[2][2][152];       // [parity][chain][152]
  __shared__ int   spk[2][NSEQ];
  __shared__ int   startA[2][NSEQ];
  __shared__ int   sLayer, sPair, sHalf;

  const int tid = threadIdx.x;

  // --- claim (layer, pair, half) with XCD-local preference; 64 slots/layer ---
  if (tid == 0){
    int xcc = 0;
    asm volatile("s_getreg_b32 %0, hwreg(HW_REG_XCC_ID)" : "=s"(xcc));
    int pref = (xcc >> 1) & 3;
    int* claimc = syncc + 3*32*16 + 3*128*2*16;
    int l = 0, p = 0, hfv = 0;
    #pragma unroll 1
    for (int t=0; t<4; ++t){
      int cand = (pref + t) & 3;
      int idx = __hip_atomic_fetch_add(&claimc[cand*16], 1, __ATOMIC_RELAXED, __HIP_MEMORY_SCOPE_AGENT);
      if (idx < 64){ l = cand; p = idx>>1; hfv = idx&1; break; }
    }
    sLayer = l; sPair = p; sHalf = hfv;
  }
  __syncthreads();
  const int layer = sLayer;
  const int pair  = sPair;
  const int hf    = sHalf;
  const int base0 = (2*pair)*NSEQ;
  const int base1 = (2*pair+1)*NSEQ;

  const uint4* Wm4 = (const uint4*)(W_M4 + (size_t)layer*38*1800*4);
  const uint4* Wr4 = (const uint4*)(WrT4 + (size_t)layer*38*600*4);
  const uint4* Wp4 = (const uint4*)(W_P4 + (size_t)layer*38*1800*4);
  const float* HinB0 = Hball + (size_t)base0*300;
  const float* HinB1 = Hball + (size_t)base1*300;
  float* HoutB0 = Hball + ((size_t)(layer+1)*NROWS + (size_t)base0)*300;
  float* HoutB1 = Hball + ((size_t)(layer+1)*NROWS + (size_t)base1)*300;
  int* cntP = syncc + (layer*32 + pair)*16;
  int* cntC = (layer>0) ? (syncc + ((layer-1)*32 + pair)*16) : (int*)0;
  const float* xin  = xrow + (size_t)(((layer-1)*32 + pair)*2)*NSEQ*300;  // layer>0
  float*       xout = xrow + (size_t)((layer*32 + pair)*2)*NSEQ*300;      // layer<3

  // h-exchange pointers: per half, 2 parity slots x (2 chains x 150) f32
  const int lp = layer*32 + pair;
  float* xhMy = xhEx + ((size_t)lp*2 + hf)*600;
  const float* xhPt = xhEx + ((size_t)lp*2 + (1-hf))*600;
  int* fEmy = syncc + 1536 + (lp*2 + hf)*16;
  const int* fEpt = syncc + 1536 + (lp*2 + (1-hf))*16;

  const int w    = tid >> 6;   // wave id 0..15
  const int lane = tid & 63;

  // ---- E mapping: chain0 = tid 0..149, chain1 = tid 256..405 ----
  int ec = -1, ert = 0;
  if (tid < 150){ ec = 0; ert = tid; }
  else if (tid >= 256 && tid < 406){ ec = 1; ert = tid - 256; }
  float bcr=0,bcz=0,bcn=0,bpr=0,bpz=0,bpn=0,wkv=0; int deE=0;
  if (ec >= 0){
    deE = hf*150 + ert;
    bcr=bhh_c[layer*900+deE]; bcz=bhh_c[layer*900+300+deE]; bcn=bhh_c[layer*900+600+deE];
    bpr=bih_p[layer*900+deE]; bpz=bih_p[layer*900+300+deE]; bpn=bih_p[layer*900+600+deE];
    wkv=gwk[layer*300+deE];
  }
  // ---- import regs (waves 0,1): partner gwk, 3 per lane ----
  float wkp0=0, wkp1=0, wkp2=0;
  if (w < 2){
    const int pbase = layer*300 + (1-hf)*150;
    wkp0 = gwk[pbase + lane];
    wkp1 = gwk[pbase + 64 + lane];
    if (lane < 22) wkp2 = gwk[pbase + 128 + lane];
  }
  // ---- D rows (serial waves): r1 = tid, r2 = tid+512 ----
  int opmD1 = 0, opmD2 = 0; bool hasD2 = false;
  if (tid < 512){
    { int g = tid/150; opmD1 = g*300 + hf*150 + (tid - g*150); }
    hasD2 = (tid < 388);
    if (hasD2){ int r2 = tid+512; int g = r2/150; opmD2 = g*300 + hf*150 + (r2 - g*150); }
  }
  // ---- P row-groups (P waves): thread pt=tid-512 (<300) owns rows
  //      {pt, 300+pt, 600+pt}, one per phase slot; all state in-phase only ----
  const int pt = tid - 512;
  const bool isPW = (tid >= 512) && (pt < 300);
  int opmPg0=0, opmPg1=0, opmPg2=0;
  float ppbPg0=0.f, ppbPg1=0.f, ppbPg2=0.f;
  if (isPW){
    int q, g, dd;
    q = pt;      g = q/150; dd = q - g*150; opmPg0 = g*300 + hf*150 + dd;
    ppbPg0 = (opmPg0<900) ? bih_c[layer*900+opmPg0] : bhh_p[layer*900+(opmPg0-900)];
    q = 300+pt;  g = q/150; dd = q - g*150; opmPg1 = g*300 + hf*150 + dd;
    ppbPg1 = (opmPg1<900) ? bih_c[layer*900+opmPg1] : bhh_p[layer*900+(opmPg1-900)];
    q = 600+pt;  g = q/150; dd = q - g*150; opmPg2 = g*300 + hf*150 + dd;
    ppbPg2 = (opmPg2<900) ? bih_c[layer*900+opmPg2] : bhh_p[layer*900+(opmPg2-900)];
  }
  const bool hasC2 = (tid < 88);   // C second row r2 = tid+512 < 600

  // ---- init LDS ----
  if (tid < 64) spk[0][tid] = speakers[base0+tid];
  else if (tid < 128) spk[1][tid-64] = speakers[base1+(tid-64)];
  for (int t=tid; t<2*1800; t+=1024) ((float*)gates)[t]=0.f;
  for (int t=tid; t<2*304; t+=1024) ((float*)Mf)[t]=0.f;
  if (tid >= 128 && tid < 168){ int t=tid-128; red[t/20][300+(t%20)] = 0.f; }
  if (tid >= 168 && tid < 176){
    int t=tid-168; f16x2 z; z.x=(_Float16)0.f; z.y=(_Float16)0.f;
    xh[t&1][(t>>1)&1][150+((t>>2)&1)] = z;   // both parities, both chains, both pad slots
  }
  if (tid >= 176 && tid < 180){
    int t=tid-176; f16x2 z; z.x=(_Float16)0.f; z.y=(_Float16)0.f;
    Mh[t>>1][150+(t&1)]=z;
    u01h[t>>1][150+(t&1)]=z; u01h[t>>1][302+(t&1)]=z;
  }
  __syncthreads();
  if (tid < 64){
    int s=0; for (int j=tid-1;j>=0;--j) if (spk[0][j]==spk[0][tid]){s=j;break;}
    startA[0][tid]=s;
  } else if (tid < 128){
    int t=tid-64;
    int s=0; for (int j=t-1;j>=0;--j) if (spk[1][j]==spk[1][t]){s=j;break;}
    startA[1][t]=s;
  }
  // producer must have finished steps 0 and 1 (R(0) + step0's R(1))
  if (layer>0 && tid==0){
    while (xloadi(cntC) < 4) __builtin_amdgcn_s_sleep(8);
  }
  __syncthreads();

  // ---- prologue R(0) -> parity 0 ----
  {
    int rcR=-1, rtR=0;
    if (tid>=128 && tid<278){ rcR=0; rtR=tid-128; }
    else if (tid>=288 && tid<438){ rcR=1; rtR=tid-288; }
    if (rcR >= 0){
      float x0, x1;
      if (layer==0){
        const float* Hin = rcR ? HinB1 : HinB0;
        float2 v = *(const float2*)(Hin + 2*rtR);
        x0=v.x; x1=v.y;
      } else {
        const float* xi = xin + (size_t)rcR*NSEQ*300;
        x0 = xload(xi + 2*rtR);
        x1 = xload(xi + 2*rtR + 1);
      }
      xf[0][rcR][2*rtR]=x0; xf[0][rcR][2*rtR+1]=x1;
      f16x2 h; h.x=(_Float16)x0; h.y=(_Float16)x1; xh[0][rcR][rtR]=h;
    }
  }
  __syncthreads();
  // ---- prologue P(0) -> pre_s[0] (all 3 row-groups back-to-back) ----
  if (isPW){
    const int np = 0;
    PGRP(opmPg0, ppbPg0);
    PGRP(opmPg1, ppbPg1);
    PGRP(opmPg2, ppbPg2);
  }
  __syncthreads();

  for (int i=0; i<NSEQ; ++i){
    const int cur = i&1, np = cur^1;

    // ---- ph1: R(i+1) on tid 128-437  ||  import+kd+softmax on waves 0,1 ----
    if (i < 63){
      int rcR=-1, rtR=0;
      if (tid>=128 && tid<278){ rcR=0; rtR=tid-128; }
      else if (tid>=288 && tid<438){ rcR=1; rtR=tid-288; }
      if (rcR >= 0){
        float x0, x1;
        if (layer==0){
          const float* Hin = rcR ? HinB1 : HinB0;
          float2 v = *(const float2*)(Hin + (size_t)(i+1)*300 + 2*rtR);
          x0=v.x; x1=v.y;
        } else {
          const float* xi = xin + (size_t)rcR*NSEQ*300 + (size_t)(i+1)*300;
          x0 = xload(xi + 2*rtR);
          x1 = xload(xi + 2*rtR + 1);
        }
        xf[np][rcR][2*rtR]=x0; xf[np][rcR][2*rtR+1]=x1;
        f16x2 h; h.x=(_Float16)x0; h.y=(_Float16)x1; xh[np][rcR][rtR]=h;
      }
    }
    if (w < 2 && i > 0){
      const int c = w;
      while (xloadi(fEpt) < i) __builtin_amdgcn_s_sleep(1);
      const int par = ((i-1)&1)*300 + c*150;
      const int pb = (1-hf)*150;
      float hv0 = xload(xhPt + par + lane);
      float hv1 = xload(xhPt + par + 64 + lane);
      float hv2 = (lane<22) ? xload(xhPt + par + 128 + lane) : 0.f;
      red[c][pb+lane] = hv0*wkp0;      Hh[c][i-1][pb+lane] = (_Float16)hv0;
      red[c][pb+64+lane] = hv1*wkp1;   Hh[c][i-1][pb+64+lane] = (_Float16)hv1;
      if (lane<22){ red[c][pb+128+lane] = hv2*wkp2; Hh[c][i-1][pb+128+lane] = (_Float16)hv2; }
      float s = red[c][lane]+red[c][lane+64]+red[c][lane+128]+red[c][lane+192]+red[c][lane+256];
      #pragma unroll
      for (int o=32;o>0;o>>=1) s += __shfl_xor(s,o);
      if (lane==0) kd[c][i-1]=s;
      {
        const int st = startA[c][i];
        const bool in = (lane>=st) && (lane<i);
        float kv = (lane==i-1) ? s : kd[c][lane];
        float a = in ? kv : -3.0e38f;
        float m = a;
        #pragma unroll
        for (int o=32;o>0;o>>=1) m = fmaxf(m,__shfl_xor(m,o));
        float e = in ? __expf(a-m) : 0.f;
        float ss = e;
        #pragma unroll
        for (int o=32;o>0;o>>=1) ss += __shfl_xor(ss,o);
        wgt[c][lane] = e/ss;
      }
    }
    __syncthreads();                                        // bar1

    // ---- ph2: B (serial)  ||  P row-group 0 ----
    if (tid < 512){
      if (i > 0){
        #pragma unroll 1
        for (int pass=0; pass<3; ++pass){
          int T = tid + pass*512;
          if (T < 1200){
            const int c = (T >= 600);
            const int t = T - c*600;
            const int d  = (t<300)? t : (t-300);
            const int wh = (t>=300);
            const int st = startA[c][i]; const int ms = spk[c][i];
            float u=0.f;
            for (int j=st;j<i;++j){
              float sel = ((spk[c][j]==ms) != (wh!=0)) ? 1.f : 0.f;
              u += sel*wgt[c][j]*(float)Hh[c][j][d];
            }
            ((_Float16*)&u01h[c][0])[(wh?304:0) + d] = (_Float16)u;
          }
        }
      }
    } else if (isPW && i < 63){
      PGRP(opmPg0, ppbPg0);
    }
    __syncthreads();                                        // bar2

    // ---- ph3: C (serial, dual-row)  ||  P row-group 1 ----
    if (tid < 512){
      if (i > 0){
        const int hh = tid&1;
        const f16x2* uA = (const f16x2*)&u01h[0][0] + hh*152;
        const f16x2* uB = (const f16x2*)&u01h[1][0] + hh*152;
        float a0=0,a1=0,a2=0,a3=0, b0=0,b1=0,b2=0,b3=0;
        float e0=0,e1=0,e2=0,e3=0, f0=0,f1=0,f2=0,f3=0;
        for (int kg=0;kg<38;kg++){
          U v1; v1.u = Wr4[(size_t)kg*600 + tid];
          U v2; if (hasC2) v2.u = Wr4[(size_t)kg*600 + tid + 512];
          f16x2 uA0=uA[kg*4+0],uA1=uA[kg*4+1],uA2=uA[kg*4+2],uA3=uA[kg*4+3];
          f16x2 uB0=uB[kg*4+0],uB1=uB[kg*4+1],uB2=uB[kg*4+2],uB3=uB[kg*4+3];
          a0=fdot2a(v1.h[0],uA0,a0); a1=fdot2a(v1.h[1],uA1,a1);
          a2=fdot2a(v1.h[2],uA2,a2); a3=fdot2a(v1.h[3],uA3,a3);
          b0=fdot2a(v1.h[0],uB0,b0); b1=fdot2a(v1.h[1],uB1,b1);
          b2=fdot2a(v1.h[2],uB2,b2); b3=fdot2a(v1.h[3],uB3,b3);
          if (hasC2){
            e0=fdot2a(v2.h[0],uA0,e0); e1=fdot2a(v2.h[1],uA1,e1);
            e2=fdot2a(v2.h[2],uA2,e2); e3=fdot2a(v2.h[3],uA3,e3);
            f0=fdot2a(v2.h[0],uB0,f0); f1=fdot2a(v2.h[1],uB1,f1);
            f2=fdot2a(v2.h[2],uB2,f2); f3=fdot2a(v2.h[3],uB3,f3);
          }
        }
        float aA = (a0+a1)+(a2+a3);
        float aB = (b0+b1)+(b2+b3);
        float m2A = aA + __shfl_xor(aA,1);
        float m2B = aB + __shfl_xor(aB,1);
        if ((tid&1)==0){ Mf[0][tid>>1] = m2A; Mf[1][tid>>1] = m2B; }
        float moA = __shfl_xor(m2A,2);
        float moB = __shfl_xor(m2B,2);
        if ((tid&3)==0){
          f16x2 hA; hA.x=(_Float16)m2A; hA.y=(_Float16)moA; Mh[0][tid>>2]=hA;
          f16x2 hB; hB.x=(_Float16)m2B; hB.y=(_Float16)moB; Mh[1][tid>>2]=hB;
        }
        if (hasC2){
          const int r2 = tid + 512;
          float cA = (e0+e1)+(e2+e3);
          float cB = (f0+f1)+(f2+f3);
          float n2A = cA + __shfl_xor(cA,1);
          float n2B = cB + __shfl_xor(cB,1);
          if ((tid&1)==0){ Mf[0][r2>>1] = n2A; Mf[1][r2>>1] = n2B; }
          float noA = __shfl_xor(n2A,2);
          float noB = __shfl_xor(n2B,2);
          if ((tid&3)==0){
            f16x2 hA; hA.x=(_Float16)n2A; hA.y=(_Float16)noA; Mh[0][r2>>2]=hA;
            f16x2 hB; hB.x=(_Float16)n2B; hB.y=(_Float16)noB; Mh[1][r2>>2]=hB;
          }
        }
      }
    } else if (isPW && i < 63){
      PGRP(opmPg1, ppbPg1);
    }
    __syncthreads();                                        // bar3

    // ---- ph4: D (serial, dual-row)  ||  P row-group 2 ----
    if (tid < 512){
      if (i > 0){
        float a0=0,a1=0,a2=0,a3=0, b0=0,b1=0,b2=0,b3=0;
        float e0=0,e1=0,e2=0,e3=0, f0=0,f1=0,f2=0,f3=0;
        for (int kg=0;kg<38;kg++){
          U v1; v1.u = Wm4[(size_t)kg*1800 + opmD1];
          U v2; if (hasD2) v2.u = Wm4[(size_t)kg*1800 + opmD2];
          f16x2 mA0=Mh[0][kg*4+0], mA1=Mh[0][kg*4+1], mA2=Mh[0][kg*4+2], mA3=Mh[0][kg*4+3];
          f16x2 mB0=Mh[1][kg*4+0], mB1=Mh[1][kg*4+1], mB2=Mh[1][kg*4+2], mB3=Mh[1][kg*4+3];
          a0=fdot2a(v1.h[0],mA0,a0); a1=fdot2a(v1.h[1],mA1,a1);
          a2=fdot2a(v1.h[2],mA2,a2); a3=fdot2a(v1.h[3],mA3,a3);
          b0=fdot2a(v1.h[0],mB0,b0); b1=fdot2a(v1.h[1],mB1,b1);
          b2=fdot2a(v1.h[2],mB2,b2); b3=fdot2a(v1.h[3],mB3,b3);
          if (hasD2){
            e0=fdot2a(v2.h[0],mA0,e0); e1=fdot2a(v2.h[1],mA1,e1);
            e2=fdot2a(v2.h[2],mA2,e2); e3=fdot2a(v2.h[3],mA3,e3);
            f0=fdot2a(v2.h[0],mB0,f0); f1=fdot2a(v2.h[1],mB1,f1);
            f2=fdot2a(v2.h[2],mB2,f2); f3=fdot2a(v2.h[3],mB3,f3);
          }
        }
        gates[0][opmD1] = (a0+a1)+(a2+a3);
        gates[1][opmD1] = (b0+b1)+(b2+b3);
        if (hasD2){
          gates[0][opmD2] = (e0+e1)+(e2+e3);
          gates[1][opmD2] = (f0+f1)+(f2+f3);
        }
      }
    } else if (isPW && i < 63){
      PGRP(opmPg2, ppbPg2);
    }
    __syncthreads();                                        // bar4

    // ---- ph5: E (serial waves; P waves idle) ----
    if (ec >= 0){
      const int de = deE;
      const float M = Mf[ec][de];
      const float* ps = pre_s[cur][ec];
      const float* gs = gates[ec];
      float r  = sigm(ps[de] + gs[de] + bcr);
      float z  = sigm(ps[300+de] + gs[300+de] + bcz);
      float n  = tanhf(ps[600+de] + r*(gs[600+de]+bcn));
      float C  = (1.f-z)*n + z*M;
      float rp = sigm(gs[900+de]+bpr + ps[900+de]);
      float zp = sigm(gs[1200+de]+bpz + ps[1200+de]);
      float np_ = tanhf(gs[1500+de]+bpn + rp*ps[1500+de]);
      float qv = xf[cur][ec][de];
      float P  = (1.f-zp)*np_ + zp*qv;
      float h  = C + P;
      Hh[ec][i][de] = (_Float16)h;
      red[ec][de] = h*wkv;
      float* Ho = ec ? HoutB1 : HoutB0;
      Ho[(size_t)i*300 + de] = h;
      xstore(xhMy + (i&1)*300 + ec*150 + ert, h);
      if (layer<3) xstore(xout + (size_t)ec*NSEQ*300 + (size_t)i*300 + de, h);
    }
    asm volatile("s_waitcnt vmcnt(0)" ::: "memory");   // drain publish before flags
    __syncthreads();                                        // bar5
    if (tid==0){
      __hip_atomic_fetch_add(fEmy, 1, __ATOMIC_RELAXED, __HIP_MEMORY_SCOPE_AGENT);
      if (layer<3) __hip_atomic_fetch_add(cntP, 1, __ATOMIC_RELAXED, __HIP_MEMORY_SCOPE_AGENT);
      if (layer>0 && i<62){
        while (xloadi(cntC) < 2*(i+3)) __builtin_amdgcn_s_sleep(8);
      }
    }
    __syncthreads();                                        // bar6
  }
}

// ---------------------------------------------------------------------------
// Head with fp16-dot2 GEMMs (unchanged).
// ---------------------------------------------------------------------------
__global__ __launch_bounds__(256) void head_kernel(
  const float* __restrict__ H0, const float* __restrict__ Hl1,
  const float* __restrict__ Hl2, const float* __restrict__ Hl3,
  const float* __restrict__ Hl4, const float* __restrict__ feat,
  const f16x2* __restrict__ W14, const float* __restrict__ b1,
  const f16x2* __restrict__ W24, const float* __restrict__ b2,
  const float* __restrict__ w3, const float* __restrict__ b3,
  float* __restrict__ out)
{
  const int tid = threadIdx.x;
  const int r0  = blockIdx.x*16;
  __shared__ f16x2 Xh[16*256];
  __shared__ _Float16 h1h[16*304];
  __shared__ float S2[16*304];
  const uint4* W14u = (const uint4*)W14;
  const uint4* W24u = (const uint4*)W24;

  float acc0[16], acc1[16];
  #pragma unroll
  for (int r=0;r<16;r++){ acc0[r]=0.f; acc1[r]=0.f; }
  const int o  = tid;
  const int o2 = tid + 256;
  const bool has2 = (o2 < 300);

  #pragma unroll
  for (int seg=0; seg<7; seg++){
    const float* src = (seg==0)?H0:(seg==1)?Hl1:(seg==2)?Hl2:(seg==3)?Hl3:(seg==4)?Hl4:feat;
    if (seg < 5){
      for (int t=tid; t<16*152; t+=256){
        int r=t/152, p=t-r*152, c=2*p;
        float v0 = (c<300)? src[(size_t)(r0+r)*300 + c] : 0.f;
        float v1 = (c+1<300)? src[(size_t)(r0+r)*300 + c+1] : 0.f;
        f16x2 h; h.x=(_Float16)v0; h.y=(_Float16)v1;
        Xh[r*256+p] = h;
      }
    } else {
      const int cb = (seg-5)*512;
      for (int t=tid; t<16*256; t+=256){
        int r=t>>8, p=t&255;
        float v0 = src[(size_t)(r0+r)*1024 + cb + 2*p];
        float v1 = src[(size_t)(r0+r)*1024 + cb + 2*p+1];
        f16x2 h; h.x=(_Float16)v0; h.y=(_Float16)v1;
        Xh[r*256+p] = h;
      }
    }
    __syncthreads();
    const int kgs = (seg<5)?38:64;
    const int kgo = (seg<5)? seg*38 : 190+(seg-5)*64;
    if (o < 300){
      for (int kg=0; kg<kgs; kg++){
        U a, b;
        a.u = W14u[(size_t)(kgo+kg)*304 + o];
        if (has2) b.u = W14u[(size_t)(kgo+kg)*304 + o2];
        #pragma unroll
        for (int r=0;r<16;r++){
          const f16x2* xp = &Xh[r*256 + kg*4];
          float t0 = fdot2a(a.h[0], xp[0], 0.f);
          t0 = fdot2a(a.h[1], xp[1], t0);
          t0 = fdot2a(a.h[2], xp[2], t0);
          t0 = fdot2a(a.h[3], xp[3], t0);
          acc0[r] += t0;
          if (has2){
            float t1 = fdot2a(b.h[0], xp[0], 0.f);
            t1 = fdot2a(b.h[1], xp[1], t1);
            t1 = fdot2a(b.h[2], xp[2], t1);
            t1 = fdot2a(b.h[3], xp[3], t1);
            acc1[r] += t1;
          }
        }
      }
    }
    __syncthreads();
  }
  if (o < 300){
    float bb = b1[o];
    #pragma unroll
    for (int r=0;r<16;r++) h1h[r*304+o] = (_Float16)fmaxf(acc0[r]+bb, 0.f);
  }
  if (has2){
    float bb = b1[o2];
    #pragma unroll
    for (int r=0;r<16;r++) h1h[r*304+o2] = (_Float16)fmaxf(acc1[r]+bb, 0.f);
  }
  if (tid < 4){
    #pragma unroll
    for (int r=0;r<16;r++) h1h[r*304+300+tid] = (_Float16)0.f;
  }
  __syncthreads();
  #pragma unroll
  for (int r=0;r<16;r++){ acc0[r]=0.f; acc1[r]=0.f; }
  if (o < 300){
    for (int kg=0; kg<38; kg++){
      U a, b;
      a.u = W24u[(size_t)kg*304 + o];
      if (has2) b.u = W24u[(size_t)kg*304 + o2];
      #pragma unroll
      for (int r=0;r<16;r++){
        const f16x2* xp = (const f16x2*)&h1h[r*304] + kg*4;
        float t0 = fdot2a(a.h[0], xp[0], 0.f);
        t0 = fdot2a(a.h[1], xp[1], t0);
        t0 = fdot2a(a.h[2], xp[2], t0);
        t0 = fdot2a(a.h[3], xp[3], t0);
        acc0[r] += t0;
        if (has2){
          float t1 = fdot2a(b.h[0], xp[0], 0.f);
          t1 = fdot2a(b.h[1], xp[1], t1);
          t1 = fdot2a(b.h[2], xp[2], t1);
          t1 = fdot2a(b.h[3], xp[3], t1);
          acc1[r] += t1;
        }
      }
    }
  }
  __syncthreads();
  if (o < 300){
    float bb = b2[o];
    #pragma unroll
    for (int r=0;r<16;r++) S2[r*304+o] = fmaxf(acc0[r]+bb, 0.f);
  }
  if (has2){
    float bb = b2[o2];
    #pragma unroll
    for (int r=0;r<16;r++) S2[r*304+o2] = fmaxf(acc1[r]+bb, 0.f);
  }
  __syncthreads();
  if (tid < 16*7){
    int r = tid/7, c = tid - r*7;
    float s = b3[c];
    const float* wrow = w3 + (size_t)c*HID;
    for (int k=0;k<300;k++) s += wrow[k]*S2[r*304+k];
    out[(size_t)(r0+r)*7 + c] = s;
  }
}

// ---------------------------------------------------------------------------
extern "C" void kernel_launch(void* const* d_in, const int* in_sizes, int n_in,
                              void* d_out, int out_size, void* d_ws, size_t ws_size,
                              hipStream_t stream)
{
  (void)in_sizes; (void)n_in; (void)out_size; (void)ws_size;
  const float* feat  = (const float*)d_in[0];
  const int*   spk   = (const int*)d_in[1];
  const float* w_in  = (const float*)d_in[2];
  const float* b_in  = (const float*)d_in[3];
  const float* gwq   = (const float*)d_in[4];
  const float* gwk   = (const float*)d_in[5];
  const float* gb    = (const float*)d_in[6];
  const float* wr0   = (const float*)d_in[7];
  const float* wr1   = (const float*)d_in[8];
  const float* wih_c = (const float*)d_in[9];
  const float* whh_c = (const float*)d_in[10];
  const float* bih_c = (const float*)d_in[11];
  const float* bhh_c = (const float*)d_in[12];
  const float* wih_p = (const float*)d_in[13];
  const float* whh_p = (const float*)d_in[14];
  const float* bih_p = (const float*)d_in[15];
  const float* bhh_p = (const float*)d_in[16];
  const float* w1    = (const float*)d_in[17];
  const float* b1    = (const float*)d_in[18];
  const float* w2    = (const float*)d_in[19];
  const float* b2    = (const float*)d_in[20];
  const float* w3    = (const float*)d_in[21];
  const float* b3    = (const float*)d_in[22];
  float* out = (float*)d_out;

  char* ws = (char*)d_ws;
  size_t off = 0;
  auto alloc = [&](size_t bytes)->void*{
    void* p = ws + off;
    off += (bytes + 255) & ~(size_t)255;
    return p;
  };
  f16x2* W_M4 = (f16x2*)alloc((size_t)4*38*1800*4 * sizeof(f16x2));
  f16x2* WrT4 = (f16x2*)alloc((size_t)4*38*600*4  * sizeof(f16x2));
  f16x2* W_P4 = (f16x2*)alloc((size_t)4*38*1800*4 * sizeof(f16x2));
  f16x2* W_H4 = (f16x2*)alloc((size_t)128*300*4   * sizeof(f16x2));
  f16x2* W_14 = (f16x2*)alloc((size_t)318*304*4   * sizeof(f16x2));
  f16x2* W_24 = (f16x2*)alloc((size_t)38*304*4    * sizeof(f16x2));
  float* Hball = (float*)alloc((size_t)5*NROWS*HID*sizeof(float));
  float* xrow  = (float*)alloc((size_t)3*64*NSEQ*HID*sizeof(float));
  int*   syncc = (int*)alloc((size_t)NSYNC*sizeof(int));
  float* xhEx  = (float*)alloc((size_t)128*2*600*sizeof(float));

  {
    const int tot = 4*38*1800*4 + 4*38*600*4 + 4*38*1800*4 + 128*300*4
                  + 318*304*4 + 38*304*4 + NSYNC;
    convert_all_kernel<<<(tot+255)/256, 256, 0, stream>>>(whh_c, wih_p, wih_c, whh_p,
        wr0, wr1, w_in, w1, w2, W_M4, WrT4, W_P4, W_H4, W_14, W_24, syncc);
  }
  h0_kernel<<<NROWS/8, 256, 0, stream>>>(feat, W_H4, b_in, Hball);

  scan_pipe_kernel<<<256, 1024, 0, stream>>>(Hball, W_M4, WrT4, W_P4,
      bih_c, bhh_c, bih_p, bhh_p, gwq, gwk, gb, spk, xrow, syncc, xhEx);

  head_kernel<<<NROWS/16, 256, 0, stream>>>(
      Hball, Hball + (size_t)NROWS*HID, Hball + (size_t)2*NROWS*HID,
      Hball + (size_t)3*NROWS*HID, Hball + (size_t)4*NROWS*HID,
      feat, W_14, b1, W_24, b2, w3, b3, out);
}

// Round 10
// 1763.510 us; speedup vs baseline: 4.4987x; 1.2486x over previous
//
#include <hip/hip_runtime.h>
#include <hip/hip_bf16.h>

typedef _Float16 f16x2 __attribute__((ext_vector_type(2)));

#define HID 300
#define NSEQ 64
#define NROWS 4096   // B*N = 64*64

union U { uint4 u; f16x2 h[4]; };

__device__ __forceinline__ float sigm(float x){ return 1.f/(1.f+__expf(-x)); }

__device__ __forceinline__ float fdot2a(f16x2 a, f16x2 b, float c){
#if __has_builtin(__builtin_amdgcn_fdot2)
  return __builtin_amdgcn_fdot2(a, b, c, false);
#else
  return c + (float)a.x*(float)b.x + (float)a.y*(float)b.y;
#endif
}

// Relaxed agent-scope ops: LLC-coherent, NO cache maintenance (no L2 flush).
__device__ __forceinline__ void xstore(float* p, float v){
  __hip_atomic_store(p, v, __ATOMIC_RELAXED, __HIP_MEMORY_SCOPE_AGENT);
}
__device__ __forceinline__ float xload(const float* p){
  return __hip_atomic_load(p, __ATOMIC_RELAXED, __HIP_MEMORY_SCOPE_AGENT);
}
__device__ __forceinline__ int xloadi(const int* p){
  return __hip_atomic_load(p, __ATOMIC_RELAXED, __HIP_MEMORY_SCOPE_AGENT);
}

// sync area layout (ints):
//   [0, 1536)            : cross-layer step counters (3 layers x 32 pairs x 16)
//   [1536, 1536+4096)    : fE flags (h-exchange, 128 pairs x 2 halves x 16)
//   [13824, 13824+64)    : claim pools (4 layers x 16)   (gap kept zeroed)
#define NSYNC (3*32*16 + 3*128*2*16 + 64)

// ---------------------------------------------------------------------------
// Merged repack: f32 -> fp16 pairs, [kg][outs][4 pairs] coalesced; also zeroes
// the pipeline sync counters + claim pools every launch.
// ---------------------------------------------------------------------------
__global__ void convert_all_kernel(
    const float* __restrict__ whh_c, const float* __restrict__ wih_p,
    const float* __restrict__ wih_c, const float* __restrict__ whh_p,
    const float* __restrict__ wr0,   const float* __restrict__ wr1,
    const float* __restrict__ w_in,  const float* __restrict__ w1,
    const float* __restrict__ w2,
    f16x2* __restrict__ W_M4, f16x2* __restrict__ WrT4, f16x2* __restrict__ W_P4,
    f16x2* __restrict__ W_H4, f16x2* __restrict__ W_14, f16x2* __restrict__ W_24,
    int* __restrict__ syncc)
{
  const int NA = 4*38*1800*4;
  const int NB = 4*38*600*4;
  const int NP = 4*38*1800*4;
  const int NH = 128*300*4;
  const int N1 = 318*304*4;
  const int N2 = 38*304*4;
  const int NS = NSYNC;
  const int TOT = NA+NB+NP+NH+N1+N2+NS;
  for (int idx0 = blockIdx.x*blockDim.x + threadIdx.x; idx0 < TOT; idx0 += gridDim.x*blockDim.x){
    int idx = idx0;
    if (idx < NA){
      int l    = idx/(38*1800*4);
      int rem  = idx - l*(38*1800*4);
      int kg   = rem/(1800*4);
      int rem2 = rem - kg*(1800*4);
      int o = rem2>>2, s = rem2&3;
      int c = (kg*4+s)*2;
      float v0=0.f, v1=0.f;
      if (c < 300){
        const float* src = (o<900) ? (whh_c + ((size_t)l*900+o)*300)
                                   : (wih_p + ((size_t)l*900+(o-900))*300);
        v0 = src[c]; v1 = src[c+1];
      }
      f16x2 t; t.x=(_Float16)v0; t.y=(_Float16)v1;
      W_M4[idx] = t; continue;
    }
    idx -= NA;
    if (idx < NB){
      int l    = idx/(38*600*4);
      int rem  = idx - l*(38*600*4);
      int kg   = rem/(600*4);
      int rem2 = rem - kg*(600*4);
      int t6 = rem2>>2, s = rem2&3;
      int d = t6>>1, hh = t6&1;
      int c = (kg*4+s)*2;
      float v0=0.f, v1=0.f;
      if (c < 300){
        const float* src = hh ? (wr1 + ((size_t)l*300+d)*300)
                              : (wr0 + ((size_t)l*300+d)*300);
        v0 = src[c]; v1 = src[c+1];
      }
      f16x2 t; t.x=(_Float16)v0; t.y=(_Float16)v1;
      WrT4[idx] = t; continue;
    }
    idx -= NB;
    if (idx < NP){
      int l    = idx/(38*1800*4);
      int rem  = idx - l*(38*1800*4);
      int kg   = rem/(1800*4);
      int rem2 = rem - kg*(1800*4);
      int o = rem2>>2, s = rem2&3;
      int c = (kg*4+s)*2;
      float v0=0.f, v1=0.f;
      if (c < 300){
        const float* src = (o<900) ? (wih_c + ((size_t)l*900+o)*300)
                                   : (whh_p + ((size_t)l*900+(o-900))*300);
        v0 = src[c]; v1 = src[c+1];
      }
      f16x2 t; t.x=(_Float16)v0; t.y=(_Float16)v1;
      W_P4[idx] = t; continue;
    }
    idx -= NP;
    if (idx < NH){
      int kg  = idx/(300*4);
      int rem = idx - kg*(300*4);
      int o = rem>>2, s = rem&3;
      int c = (kg*4+s)*2;
      f16x2 t; t.x=(_Float16)w_in[(size_t)o*1024+c]; t.y=(_Float16)w_in[(size_t)o*1024+c+1];
      W_H4[idx] = t; continue;
    }
    idx -= NH;
    if (idx < N1){
      int kgg = idx/(304*4);
      int rem = idx - kgg*(304*4);
      int o = rem>>2, s = rem&3;
      int segbase, seglen, kgl;
      if (kgg < 190){ int seg = kgg/38; kgl = kgg - seg*38; segbase = seg*300; seglen = 300; }
      else { int kk = kgg-190; int sf = kk>>6; kgl = kk&63; segbase = 1500 + sf*512; seglen = 512; }
      int c = (kgl*4+s)*2;
      float v0=0.f, v1=0.f;
      if (o < 300 && c < seglen){
        v0 = w1[(size_t)o*2524 + segbase + c];
        if (c+1 < seglen) v1 = w1[(size_t)o*2524 + segbase + c + 1];
      }
      f16x2 t; t.x=(_Float16)v0; t.y=(_Float16)v1;
      W_14[idx] = t; continue;
    }
    idx -= N1;
    if (idx < N2){
      int kg = idx/(304*4);
      int rem = idx - kg*(304*4);
      int o = rem>>2, s = rem&3;
      int c = (kg*4+s)*2;
      float v0=0.f, v1=0.f;
      if (o < 300 && c < 300){ v0 = w2[(size_t)o*300+c]; v1 = w2[(size_t)o*300+c+1]; }
      f16x2 t; t.x=(_Float16)v0; t.y=(_Float16)v1;
      W_24[idx] = t; continue;
    }
    idx -= N2;
    syncc[idx] = 0;
  }
}

// ---------------------------------------------------------------------------
// H0 = relu(features @ w_in^T + b_in), coalesced fp16 weights.
// ---------------------------------------------------------------------------
__global__ __launch_bounds__(256) void h0_kernel(const float* __restrict__ feat,
    const f16x2* __restrict__ WH, const float* __restrict__ b_in, float* __restrict__ H0)
{
  const int tid = threadIdx.x;
  const int r0  = blockIdx.x*8;
  __shared__ f16x2 X[8][512];
  for (int t=tid; t<8*512; t+=256){
    int r=t>>9, p=t&511, c=2*p;
    f16x2 h; h.x=(_Float16)feat[(size_t)(r0+r)*1024+c];
    h.y=(_Float16)feat[(size_t)(r0+r)*1024+c+1];
    X[r][p]=h;
  }
  __syncthreads();
  const uint4* WHu = (const uint4*)WH;
  const int o0 = tid, o1 = tid+256;
  const bool h1v = (o1 < 300);
  float acc[2][8];
  #pragma unroll
  for (int j=0;j<2;j++)
    #pragma unroll
    for (int r=0;r<8;r++) acc[j][r]=0.f;
  for (int kg=0; kg<128; kg++){
    U w0, w1;
    w0.u = WHu[(size_t)kg*300 + o0];
    if (h1v) w1.u = WHu[(size_t)kg*300 + o1];
    #pragma unroll
    for (int r=0;r<8;r++){
      const f16x2* xp = &X[r][kg*4];
      f16x2 x0=xp[0],x1=xp[1],x2=xp[2],x3=xp[3];
      acc[0][r] = fdot2a(w0.h[3],x3, fdot2a(w0.h[2],x2, fdot2a(w0.h[1],x1, fdot2a(w0.h[0],x0, acc[0][r]))));
      if (h1v)
        acc[1][r] = fdot2a(w1.h[3],x3, fdot2a(w1.h[2],x2, fdot2a(w1.h[1],x1, fdot2a(w1.h[0],x0, acc[1][r]))));
    }
  }
  {
    float bb = b_in[o0];
    #pragma unroll
    for (int r=0;r<8;r++) H0[(size_t)(r0+r)*HID + o0] = fmaxf(acc[0][r]+bb, 0.f);
  }
  if (h1v){
    float bb = b_in[o1];
    #pragma unroll
    for (int r=0;r<8;r++) H0[(size_t)(r0+r)*HID + o1] = fmaxf(acc[1][r]+bb, 0.f);
  }
}

// ---------------------------------------------------------------------------
// Fused 4-layer pipelined scan, d-SPLIT paired WGs: 256 WGs = 4 layers x
// 32 pairs x 2 halves. Half h owns gate-column range d in [150h,150h+150).
// The {poll, partner-h import, kd reduce, softmax} chain runs on waves 0 and
// 8 ONLY (one chain per wave, fully in-wave), CONCURRENT with the P weight
// stream on waves 1-7/9-15 (896 threads cover P rows 0-895; wave 0 lanes 0-3
// mop up rows 896-899 after softmax). Verified best structure (R5: scan
// 1236us, total 1744us). Wave-specialized P variants (R6-R9) all regressed:
// cross-barrier accumulators spill at the 64-VGPR cap, and dual-row serial
// phases double the critical path. Do not re-attempt without new evidence.
// ---------------------------------------------------------------------------
__global__ __launch_bounds__(1024) void scan_pipe_kernel(
  float* __restrict__ Hball,
  const f16x2* __restrict__ W_M4, const f16x2* __restrict__ WrT4, const f16x2* __restrict__ W_P4,
  const float* __restrict__ bih_c, const float* __restrict__ bhh_c,
  const float* __restrict__ bih_p, const float* __restrict__ bhh_p,
  const float* __restrict__ gwq, const float* __restrict__ gwk, const float* __restrict__ gbv,
  const int* __restrict__ speakers, float* __restrict__ xrow, int* __restrict__ syncc,
  float* __restrict__ xhEx)
{
  (void)gwq; (void)gbv;   // softmax is shift-invariant: q and b cancel exactly
  __shared__ _Float16 Hh[2][NSEQ][304];
  __shared__ float pre_s[2][1800];
  __shared__ float gates[2][1800];
  __shared__ float Mf[2][304];
  __shared__ f16x2 Mh[2][152];
  __shared__ f16x2 u01h[2][304];
  __shared__ float wgt[2][NSEQ];
  __shared__ float kd[2][NSEQ];
  __shared__ float red[2][320];
  __shared__ float xf[2][304];
  __shared__ f16x2 xh[2][152];
  __shared__ int   spk[2][NSEQ];
  __shared__ int   startA[2][NSEQ];
  __shared__ int   sLayer, sPair, sHalf;

  const int tid = threadIdx.x;

  // --- claim (layer, pair, half) with XCD-local preference; 64 slots/layer ---
  if (tid == 0){
    int xcc = 0;
    asm volatile("s_getreg_b32 %0, hwreg(HW_REG_XCC_ID)" : "=s"(xcc));
    int pref = (xcc >> 1) & 3;
    int* claimc = syncc + 3*32*16 + 3*128*2*16;
    int l = 0, p = 0, hf = 0;
    #pragma unroll 1
    for (int t=0; t<4; ++t){
      int cand = (pref + t) & 3;
      int idx = __hip_atomic_fetch_add(&claimc[cand*16], 1, __ATOMIC_RELAXED, __HIP_MEMORY_SCOPE_AGENT);
      if (idx < 64){ l = cand; p = idx>>1; hf = idx&1; break; }
    }
    sLayer = l; sPair = p; sHalf = hf;
  }
  __syncthreads();
  const int layer = sLayer;
  const int pair  = sPair;
  const int hf    = sHalf;
  const int base0 = (2*pair)*NSEQ;
  const int base1 = (2*pair+1)*NSEQ;

  const uint4* Wm4 = (const uint4*)(W_M4 + (size_t)layer*38*1800*4);
  const uint4* Wr4 = (const uint4*)(WrT4 + (size_t)layer*38*600*4);
  const uint4* Wp4 = (const uint4*)(W_P4 + (size_t)layer*38*1800*4);
  const float* HinB0 = Hball + (size_t)base0*300;
  const float* HinB1 = Hball + (size_t)base1*300;
  float* HoutB0 = Hball + ((size_t)(layer+1)*NROWS + (size_t)base0)*300;
  float* HoutB1 = Hball + ((size_t)(layer+1)*NROWS + (size_t)base1)*300;
  int* cntP = syncc + (layer*32 + pair)*16;
  int* cntC = (layer>0) ? (syncc + ((layer-1)*32 + pair)*16) : (int*)0;
  const float* xin  = xrow + (size_t)(((layer-1)*32 + pair)*2)*NSEQ*300;  // layer>0
  float*       xout = xrow + (size_t)((layer*32 + pair)*2)*NSEQ*300;      // layer<3

  // h-exchange pointers: per half, 2 parity slots x (2 chains x 150) f32
  const int lp = layer*32 + pair;
  float* xhMy = xhEx + ((size_t)lp*2 + hf)*600;
  const float* xhPt = xhEx + ((size_t)lp*2 + (1-hf))*600;
  int* fEmy = syncc + 1536 + (lp*2 + hf)*16;
  const int* fEpt = syncc + 1536 + (lp*2 + (1-hf))*16;

  const int w    = tid >> 6;   // wave id 0..15
  const int rc   = tid >> 9;   // half 0/1 (chain for R/E phases)
  const int rt   = tid & 511;
  const int lane = tid & 63;

  // E-phase per-thread regs (my d-range: d = hf*150 + rt, rt<150)
  float bcr=0,bcz=0,bcn=0,bpr=0,bpz=0,bpn=0,wkv=0;
  if (rt < 150){
    const int de = hf*150 + rt;
    bcr=bhh_c[layer*900+de]; bcz=bhh_c[layer*900+300+de]; bcn=bhh_c[layer*900+600+de];
    bpr=bih_p[layer*900+de]; bpz=bih_p[layer*900+300+de]; bpn=bih_p[layer*900+600+de];
    wkv=gwk[layer*300+de];
  }
  // import regs for waves 0/8: partner gwk values, 3 per lane
  float wkp0=0, wkp1=0, wkp2=0;
  if (w==0 || w==8){
    const int pbase = layer*300 + (1-hf)*150;
    wkp0 = gwk[pbase + lane];
    wkp1 = gwk[pbase + 64 + lane];
    if (lane < 22) wkp2 = gwk[pbase + 128 + lane];
  }

  // P mapping: waves 1-7,9-15 -> pidx 0..895 -> row rr=pidx; wave0 lanes 0-3 rows 896-899
  const bool isP = (w != 0) && (w != 8);
  int opmP = 0; float ppbP = 0.f;
  if (isP){
    const int pidx = (tid < 512) ? (tid - 64) : (tid - 128);   // 0..895
    const int g = pidx/150;
    const int dd = pidx - g*150;
    opmP = g*300 + hf*150 + dd;
    ppbP = (opmP<900) ? bih_c[layer*900+opmP] : bhh_p[layer*900+(opmP-900)];
  }
  int opmX = 0; float ppbX = 0.f;
  if (w==0 && lane<4){
    const int rr = 896 + lane;           // g=5, dd=rr-750
    opmX = 1500 + hf*150 + (rr - 750);
    ppbX = (opmX<900) ? bih_c[layer*900+opmX] : bhh_p[layer*900+(opmX-900)];
  }

  // D output mapping: tid<900 -> opm = (tid/150)*300 + hf*150 + tid%150
  int opm = 0;
  if (tid < 900){
    const int g = tid/150;
    const int dd = tid - g*150;
    opm = g*300 + hf*150 + dd;
  }

  // init
  if (tid < 64) spk[0][tid] = speakers[base0+tid];
  else if (tid < 128) spk[1][tid-64] = speakers[base1+(tid-64)];
  for (int t=tid; t<2*1800; t+=1024) ((float*)gates)[t]=0.f;
  for (int t=tid; t<2*304; t+=1024) ((float*)Mf)[t]=0.f;
  if (tid >= 128 && tid < 168){ int t=tid-128; red[t/20][300+(t%20)] = 0.f; }
  if (tid >= 168 && tid < 176){ int t=tid-168; xf[t>>2][300+(t&3)] = 0.f; }
  if (tid >= 176 && tid < 180){
    int t=tid-176; f16x2 z; z.x=(_Float16)0.f; z.y=(_Float16)0.f;
    Mh[t>>1][150+(t&1)]=z; xh[t>>1][150+(t&1)]=z;
    u01h[t>>1][150+(t&1)]=z; u01h[t>>1][302+(t&1)]=z;
  }
  __syncthreads();
  if (tid < 64){
    int s=0; for (int j=tid-1;j>=0;--j) if (spk[0][j]==spk[0][tid]){s=j;break;}
    startA[0][tid]=s;
  } else if (tid < 128){
    int t=tid-64;
    int s=0; for (int j=t-1;j>=0;--j) if (spk[1][j]==spk[1][t]){s=j;break;}
    startA[1][t]=s;
  }
  if (layer>0 && tid==0){
    while (xloadi(cntC) < 2) __builtin_amdgcn_s_sleep(8);   // row 0: both halves
  }
  __syncthreads();

  for (int i=0; i<NSEQ; ++i){
    // R: receive/load input row i for both chains (full 300 per chain)
    if (rt < 150){
      float x0, x1;
      if (layer==0){
        const float* Hin = rc ? HinB1 : HinB0;
        float2 v = *(const float2*)(Hin + (size_t)i*300 + 2*rt);
        x0=v.x; x1=v.y;
      } else {
        const float* xi = xin + (size_t)rc*NSEQ*300 + (size_t)i*300;
        x0 = xload(xi + 2*rt);
        x1 = xload(xi + 2*rt + 1);
      }
      xf[rc][2*rt]=x0; xf[rc][2*rt+1]=x1;
      f16x2 h; h.x=(_Float16)x0; h.y=(_Float16)x1; xh[rc][rt]=h;
    }
    __syncthreads();                                        // (1)

    // {P weight stream on waves 1-7,9-15}  ||  {poll+import+kd+softmax on waves 0,8}
    if (isP){
      float aA0=0,aA1=0,aA2=0,aA3=0, aB0=0,aB1=0,aB2=0,aB3=0;
      for (int kg=0;kg<38;kg++){
        U v; v.u = Wp4[(size_t)kg*1800 + opmP];
        f16x2 xA0=xh[0][kg*4+0],xA1=xh[0][kg*4+1],xA2=xh[0][kg*4+2],xA3=xh[0][kg*4+3];
        f16x2 xB0=xh[1][kg*4+0],xB1=xh[1][kg*4+1],xB2=xh[1][kg*4+2],xB3=xh[1][kg*4+3];
        aA0=fdot2a(v.h[0],xA0,aA0); aA1=fdot2a(v.h[1],xA1,aA1);
        aA2=fdot2a(v.h[2],xA2,aA2); aA3=fdot2a(v.h[3],xA3,aA3);
        aB0=fdot2a(v.h[0],xB0,aB0); aB1=fdot2a(v.h[1],xB1,aB1);
        aB2=fdot2a(v.h[2],xB2,aB2); aB3=fdot2a(v.h[3],xB3,aB3);
      }
      pre_s[0][opmP] = (aA0+aA1)+(aA2+aA3) + ppbP;
      pre_s[1][opmP] = (aB0+aB1)+(aB2+aB3) + ppbP;
    } else if (i > 0){
      const int c = (w==8);
      // poll partner E(i-1) completion (uniform branch, broadcast load)
      while (xloadi(fEpt) < i) __builtin_amdgcn_s_sleep(1);
      // import partner h(i-1): 150 values, 3 per lane
      const int par = ((i-1)&1)*300 + c*150;
      const int pb = (1-hf)*150;
      float hv0 = xload(xhPt + par + lane);
      float hv1 = xload(xhPt + par + 64 + lane);
      float hv2 = (lane<22) ? xload(xhPt + par + 128 + lane) : 0.f;
      red[c][pb+lane] = hv0*wkp0;      Hh[c][i-1][pb+lane] = (_Float16)hv0;
      red[c][pb+64+lane] = hv1*wkp1;   Hh[c][i-1][pb+64+lane] = (_Float16)hv1;
      if (lane<22){ red[c][pb+128+lane] = hv2*wkp2; Hh[c][i-1][pb+128+lane] = (_Float16)hv2; }
      // kd[c][i-1] reduce + softmax -> wgt for this step's B (all in-wave)
      float s = red[c][lane]+red[c][lane+64]+red[c][lane+128]+red[c][lane+192]+red[c][lane+256];
      #pragma unroll
      for (int o=32;o>0;o>>=1) s += __shfl_xor(s,o);
      if (lane==0) kd[c][i-1]=s;
      {
        const int st = startA[c][i];
        const bool in = (lane>=st) && (lane<i);
        float kv = (lane==i-1) ? s : kd[c][lane];
        float a = in ? kv : -3.0e38f;
        float m = a;
        #pragma unroll
        for (int o=32;o>0;o>>=1) m = fmaxf(m,__shfl_xor(m,o));
        float e = in ? __expf(a-m) : 0.f;
        float ss = e;
        #pragma unroll
        for (int o=32;o>0;o>>=1) ss += __shfl_xor(ss,o);
        wgt[c][lane] = e/ss;
      }
    }
    // wave 0 lanes 0-3: P rows 896-899 (after import/softmax; idle lanes otherwise)
    if (w==0 && lane<4){
      float aA0=0,aA1=0,aA2=0,aA3=0, aB0=0,aB1=0,aB2=0,aB3=0;
      for (int kg=0;kg<38;kg++){
        U v; v.u = Wp4[(size_t)kg*1800 + opmX];
        f16x2 xA0=xh[0][kg*4+0],xA1=xh[0][kg*4+1],xA2=xh[0][kg*4+2],xA3=xh[0][kg*4+3];
        f16x2 xB0=xh[1][kg*4+0],xB1=xh[1][kg*4+1],xB2=xh[1][kg*4+2],xB3=xh[1][kg*4+3];
        aA0=fdot2a(v.h[0],xA0,aA0); aA1=fdot2a(v.h[1],xA1,aA1);
        aA2=fdot2a(v.h[2],xA2,aA2); aA3=fdot2a(v.h[3],xA3,aA3);
        aB0=fdot2a(v.h[0],xB0,aB0); aB1=fdot2a(v.h[1],xB1,aB1);
        aB2=fdot2a(v.h[2],xB2,aB2); aB3=fdot2a(v.h[3],xB3,aB3);
      }
      pre_s[0][opmX] = (aA0+aA1)+(aA2+aA3) + ppbX;
      pre_s[1][opmX] = (aB0+aB1)+(aB2+aB3) + ppbX;
    }
    __syncthreads();                                        // (2)

    if (i > 0){
      // B: weighted history sums, full 1200 tasks (needs full Hh)
      #pragma unroll 1
      for (int pass=0; pass<2; ++pass){
        int T = tid + pass*1024;
        if (T < 1200){
          const int c = (T >= 600);
          const int t = T - c*600;
          const int d  = (t<300)? t : (t-300);
          const int wh = (t>=300);
          const int st = startA[c][i]; const int ms = spk[c][i];
          float u=0.f;
          for (int j=st;j<i;++j){
            float sel = ((spk[c][j]==ms) != (wh!=0)) ? 1.f : 0.f;
            u += sel*wgt[c][j]*(float)Hh[c][j][d];
          }
          ((_Float16*)&u01h[c][0])[(wh?304:0) + d] = (_Float16)u;
        }
      }
      __syncthreads();                                      // (3)
      // C: M = wr0@u0 + wr1@u1 — FULL redundant (M then local for D and E)
      if (tid < 600){
        const int hh = tid&1;
        const f16x2* uA = (const f16x2*)&u01h[0][0] + hh*152;
        const f16x2* uB = (const f16x2*)&u01h[1][0] + hh*152;
        float a0=0,a1=0,a2=0,a3=0, b0=0,b1=0,b2=0,b3=0;
        for (int kg=0;kg<38;kg++){
          U v; v.u = Wr4[(size_t)kg*600 + tid];
          a0=fdot2a(v.h[0],uA[kg*4+0],a0); a1=fdot2a(v.h[1],uA[kg*4+1],a1);
          a2=fdot2a(v.h[2],uA[kg*4+2],a2); a3=fdot2a(v.h[3],uA[kg*4+3],a3);
          b0=fdot2a(v.h[0],uB[kg*4+0],b0); b1=fdot2a(v.h[1],uB[kg*4+1],b1);
          b2=fdot2a(v.h[2],uB[kg*4+2],b2); b3=fdot2a(v.h[3],uB[kg*4+3],b3);
        }
        float aA = (a0+a1)+(a2+a3);
        float aB = (b0+b1)+(b2+b3);
        float m2A = aA + __shfl_xor(aA,1);
        float m2B = aB + __shfl_xor(aB,1);
        if ((tid&1)==0){ Mf[0][tid>>1] = m2A; Mf[1][tid>>1] = m2B; }
        float moA = __shfl_xor(m2A,2);
        float moB = __shfl_xor(m2B,2);
        if ((tid&3)==0){
          f16x2 hA; hA.x=(_Float16)m2A; hA.y=(_Float16)moA; Mh[0][tid>>2]=hA;
          f16x2 hB; hB.x=(_Float16)m2B; hB.y=(_Float16)moB; Mh[1][tid>>2]=hB;
        }
      }
      __syncthreads();                                      // (4)
      // D: gates = [whh_c ; wih_p] @ M — my 900 d-split rows
      if (tid < 900){
        float aA0=0,aA1=0,aA2=0,aA3=0, aB0=0,aB1=0,aB2=0,aB3=0;
        for (int kg=0;kg<38;kg++){
          U v; v.u = Wm4[(size_t)kg*1800 + opm];
          f16x2 mA0=Mh[0][kg*4+0], mA1=Mh[0][kg*4+1], mA2=Mh[0][kg*4+2], mA3=Mh[0][kg*4+3];
          f16x2 mB0=Mh[1][kg*4+0], mB1=Mh[1][kg*4+1], mB2=Mh[1][kg*4+2], mB3=Mh[1][kg*4+3];
          aA0=fdot2a(v.h[0],mA0,aA0); aA1=fdot2a(v.h[1],mA1,aA1);
          aA2=fdot2a(v.h[2],mA2,aA2); aA3=fdot2a(v.h[3],mA3,aA3);
          aB0=fdot2a(v.h[0],mB0,aB0); aB1=fdot2a(v.h[1],mB1,aB1);
          aB2=fdot2a(v.h[2],mB2,aB2); aB3=fdot2a(v.h[3],mB3,aB3);
        }
        gates[0][opm] = (aA0+aA1)+(aA2+aA3);
        gates[1][opm] = (aB0+aB1)+(aB2+aB3);
      }
      __syncthreads();                                      // (5)
    }
    // E: GRU combine for my d-range only (pre_s/gates/Mf all local)
    if (rt < 150){
      const int de = hf*150 + rt;
      const float M = Mf[rc][de];
      const float* ps = pre_s[rc];
      const float* gs = gates[rc];
      float r  = sigm(ps[de] + gs[de] + bcr);
      float z  = sigm(ps[300+de] + gs[300+de] + bcz);
      float n  = tanhf(ps[600+de] + r*(gs[600+de]+bcn));
      float C  = (1.f-z)*n + z*M;
      float rp = sigm(gs[900+de]+bpr + ps[900+de]);
      float zp = sigm(gs[1200+de]+bpz + ps[1200+de]);
      float np = tanhf(gs[1500+de]+bpn + rp*ps[1500+de]);
      float qv = xf[rc][de];
      float P  = (1.f-zp)*np + zp*qv;
      float h  = C + P;
      Hh[rc][i][de] = (_Float16)h;
      red[rc][de] = h*wkv;
      float* Ho = rc ? HoutB1 : HoutB0;
      Ho[(size_t)i*300 + de] = h;
      xstore(xhMy + (i&1)*300 + rc*150 + rt, h);
      if (layer<3) xstore(xout + (size_t)rc*NSEQ*300 + (size_t)i*300 + de, h);
    }
    asm volatile("s_waitcnt vmcnt(0)" ::: "memory");   // drain publish before flags
    __syncthreads();                                        // (6)
    if (tid==0){
      __hip_atomic_fetch_add(fEmy, 1, __ATOMIC_RELAXED, __HIP_MEMORY_SCOPE_AGENT);
      if (layer<3) __hip_atomic_fetch_add(cntP, 1, __ATOMIC_RELAXED, __HIP_MEMORY_SCOPE_AGENT);
      if (layer>0 && i<63){
        while (xloadi(cntC) < 2*(i+2)) __builtin_amdgcn_s_sleep(8);
      }
    }
    __syncthreads();                                        // (7)
  }
}

// ---------------------------------------------------------------------------
// Head with fp16-dot2 GEMMs (unchanged).
// ---------------------------------------------------------------------------
__global__ __launch_bounds__(256) void head_kernel(
  const float* __restrict__ H0, const float* __restrict__ Hl1,
  const float* __restrict__ Hl2, const float* __restrict__ Hl3,
  const float* __restrict__ Hl4, const float* __restrict__ feat,
  const f16x2* __restrict__ W14, const float* __restrict__ b1,
  const f16x2* __restrict__ W24, const float* __restrict__ b2,
  const float* __restrict__ w3, const float* __restrict__ b3,
  float* __restrict__ out)
{
  const int tid = threadIdx.x;
  const int r0  = blockIdx.x*16;
  __shared__ f16x2 Xh[16*256];
  __shared__ _Float16 h1h[16*304];
  __shared__ float S2[16*304];
  const uint4* W14u = (const uint4*)W14;
  const uint4* W24u = (const uint4*)W24;

  float acc0[16], acc1[16];
  #pragma unroll
  for (int r=0;r<16;r++){ acc0[r]=0.f; acc1[r]=0.f; }
  const int o  = tid;
  const int o2 = tid + 256;
  const bool has2 = (o2 < 300);

  #pragma unroll
  for (int seg=0; seg<7; seg++){
    const float* src = (seg==0)?H0:(seg==1)?Hl1:(seg==2)?Hl2:(seg==3)?Hl3:(seg==4)?Hl4:feat;
    if (seg < 5){
      for (int t=tid; t<16*152; t+=256){
        int r=t/152, p=t-r*152, c=2*p;
        float v0 = (c<300)? src[(size_t)(r0+r)*300 + c] : 0.f;
        float v1 = (c+1<300)? src[(size_t)(r0+r)*300 + c+1] : 0.f;
        f16x2 h; h.x=(_Float16)v0; h.y=(_Float16)v1;
        Xh[r*256+p] = h;
      }
    } else {
      const int cb = (seg-5)*512;
      for (int t=tid; t<16*256; t+=256){
        int r=t>>8, p=t&255;
        float v0 = src[(size_t)(r0+r)*1024 + cb + 2*p];
        float v1 = src[(size_t)(r0+r)*1024 + cb + 2*p+1];
        f16x2 h; h.x=(_Float16)v0; h.y=(_Float16)v1;
        Xh[r*256+p] = h;
      }
    }
    __syncthreads();
    const int kgs = (seg<5)?38:64;
    const int kgo = (seg<5)? seg*38 : 190+(seg-5)*64;
    if (o < 300){
      for (int kg=0; kg<kgs; kg++){
        U a, b;
        a.u = W14u[(size_t)(kgo+kg)*304 + o];
        if (has2) b.u = W14u[(size_t)(kgo+kg)*304 + o2];
        #pragma unroll
        for (int r=0;r<16;r++){
          const f16x2* xp = &Xh[r*256 + kg*4];
          float t0 = fdot2a(a.h[0], xp[0], 0.f);
          t0 = fdot2a(a.h[1], xp[1], t0);
          t0 = fdot2a(a.h[2], xp[2], t0);
          t0 = fdot2a(a.h[3], xp[3], t0);
          acc0[r] += t0;
          if (has2){
            float t1 = fdot2a(b.h[0], xp[0], 0.f);
            t1 = fdot2a(b.h[1], xp[1], t1);
            t1 = fdot2a(b.h[2], xp[2], t1);
            t1 = fdot2a(b.h[3], xp[3], t1);
            acc1[r] += t1;
          }
        }
      }
    }
    __syncthreads();
  }
  if (o < 300){
    float bb = b1[o];
    #pragma unroll
    for (int r=0;r<16;r++) h1h[r*304+o] = (_Float16)fmaxf(acc0[r]+bb, 0.f);
  }
  if (has2){
    float bb = b1[o2];
    #pragma unroll
    for (int r=0;r<16;r++) h1h[r*304+o2] = (_Float16)fmaxf(acc1[r]+bb, 0.f);
  }
  if (tid < 4){
    #pragma unroll
    for (int r=0;r<16;r++) h1h[r*304+300+tid] = (_Float16)0.f;
  }
  __syncthreads();
  #pragma unroll
  for (int r=0;r<16;r++){ acc0[r]=0.f; acc1[r]=0.f; }
  if (o < 300){
    for (int kg=0; kg<38; kg++){
      U a, b;
      a.u = W24u[(size_t)kg*304 + o];
      if (has2) b.u = W24u[(size_t)kg*304 + o2];
      #pragma unroll
      for (int r=0;r<16;r++){
        const f16x2* xp = (const f16x2*)&h1h[r*304] + kg*4;
        float t0 = fdot2a(a.h[0], xp[0], 0.f);
        t0 = fdot2a(a.h[1], xp[1], t0);
        t0 = fdot2a(a.h[2], xp[2], t0);
        t0 = fdot2a(a.h[3], xp[3], t0);
        acc0[r] += t0;
        if (has2){
          float t1 = fdot2a(b.h[0], xp[0], 0.f);
          t1 = fdot2a(b.h[1], xp[1], t1);
          t1 = fdot2a(b.h[2], xp[2], t1);
          t1 = fdot2a(b.h[3], xp[3], t1);
          acc1[r] += t1;
        }
      }
    }
  }
  __syncthreads();
  if (o < 300){
    float bb = b2[o];
    #pragma unroll
    for (int r=0;r<16;r++) S2[r*304+o] = fmaxf(acc0[r]+bb, 0.f);
  }
  if (has2){
    float bb = b2[o2];
    #pragma unroll
    for (int r=0;r<16;r++) S2[r*304+o2] = fmaxf(acc1[r]+bb, 0.f);
  }
  __syncthreads();
  if (tid < 16*7){
    int r = tid/7, c = tid - r*7;
    float s = b3[c];
    const float* wrow = w3 + (size_t)c*HID;
    for (int k=0;k<300;k++) s += wrow[k]*S2[r*304+k];
    out[(size_t)(r0+r)*7 + c] = s;
  }
}

// ---------------------------------------------------------------------------
extern "C" void kernel_launch(void* const* d_in, const int* in_sizes, int n_in,
                              void* d_out, int out_size, void* d_ws, size_t ws_size,
                              hipStream_t stream)
{
  (void)in_sizes; (void)n_in; (void)out_size; (void)ws_size;
  const float* feat  = (const float*)d_in[0];
  const int*   spk   = (const int*)d_in[1];
  const float* w_in  = (const float*)d_in[2];
  const float* b_in  = (const float*)d_in[3];
  const float* gwq   = (const float*)d_in[4];
  const float* gwk   = (const float*)d_in[5];
  const float* gb    = (const float*)d_in[6];
  const float* wr0   = (const float*)d_in[7];
  const float* wr1   = (const float*)d_in[8];
  const float* wih_c = (const float*)d_in[9];
  const float* whh_c = (const float*)d_in[10];
  const float* bih_c = (const float*)d_in[11];
  const float* bhh_c = (const float*)d_in[12];
  const float* wih_p = (const float*)d_in[13];
  const float* whh_p = (const float*)d_in[14];
  const float* bih_p = (const float*)d_in[15];
  const float* bhh_p = (const float*)d_in[16];
  const float* w1    = (const float*)d_in[17];
  const float* b1    = (const float*)d_in[18];
  const float* w2    = (const float*)d_in[19];
  const float* b2    = (const float*)d_in[20];
  const float* w3    = (const float*)d_in[21];
  const float* b3    = (const float*)d_in[22];
  float* out = (float*)d_out;

  char* ws = (char*)d_ws;
  size_t off = 0;
  auto alloc = [&](size_t bytes)->void*{
    void* p = ws + off;
    off += (bytes + 255) & ~(size_t)255;
    return p;
  };
  f16x2* W_M4 = (f16x2*)alloc((size_t)4*38*1800*4 * sizeof(f16x2));
  f16x2* WrT4 = (f16x2*)alloc((size_t)4*38*600*4  * sizeof(f16x2));
  f16x2* W_P4 = (f16x2*)alloc((size_t)4*38*1800*4 * sizeof(f16x2));
  f16x2* W_H4 = (f16x2*)alloc((size_t)128*300*4   * sizeof(f16x2));
  f16x2* W_14 = (f16x2*)alloc((size_t)318*304*4   * sizeof(f16x2));
  f16x2* W_24 = (f16x2*)alloc((size_t)38*304*4    * sizeof(f16x2));
  float* Hball = (float*)alloc((size_t)5*NROWS*HID*sizeof(float));
  float* xrow  = (float*)alloc((size_t)3*64*NSEQ*HID*sizeof(float));
  int*   syncc = (int*)alloc((size_t)NSYNC*sizeof(int));
  float* xhEx  = (float*)alloc((size_t)128*2*600*sizeof(float));

  {
    const int tot = 4*38*1800*4 + 4*38*600*4 + 4*38*1800*4 + 128*300*4
                  + 318*304*4 + 38*304*4 + NSYNC;
    convert_all_kernel<<<(tot+255)/256, 256, 0, stream>>>(whh_c, wih_p, wih_c, whh_p,
        wr0, wr1, w_in, w1, w2, W_M4, WrT4, W_P4, W_H4, W_14, W_24, syncc);
  }
  h0_kernel<<<NROWS/8, 256, 0, stream>>>(feat, W_H4, b_in, Hball);

  scan_pipe_kernel<<<256, 1024, 0, stream>>>(Hball, W_M4, WrT4, W_P4,
      bih_c, bhh_c, bih_p, bhh_p, gwq, gwk, gb, spk, xrow, syncc, xhEx);

  head_kernel<<<NROWS/16, 256, 0, stream>>>(
      Hball, Hball + (size_t)NROWS*HID, Hball + (size_t)2*NROWS*HID,
      Hball + (size_t)3*NROWS*HID, Hball + (size_t)4*NROWS*HID,
      feat, W_14, b1, W_24, b2, w3, b3, out);
}